// Round 1
// baseline (1205.661 us; speedup 1.0000x reference)
//
#include <hip/hip_runtime.h>

#define D 128

// ---------------- kernels ----------------

__global__ void k_build_qid(const int* __restrict__ s, int* __restrict__ qid,
                            int* __restrict__ uniq, int* __restrict__ counters, int S) {
  int i = blockIdx.x * blockDim.x + threadIdx.x;
  if (i >= S) return;
  int n = s[i];
  if (atomicCAS(&qid[n], -1, -2) == -1) {
    int u = atomicAdd(&counters[0], 1);
    uniq[u] = n;
    qid[n] = u;   // visible to later kernels (kernel boundary)
  }
}

// v = [Wp@asp, Wp@adp, Wc@asc, Wc@adc], each length D
__global__ void k_calc_v(const float* __restrict__ Wp, const float* __restrict__ asp,
                         const float* __restrict__ adp, const float* __restrict__ Wc,
                         const float* __restrict__ asc, const float* __restrict__ adc,
                         float* __restrict__ v) {
  int k = threadIdx.x;  // 0..127
  float s0 = 0.f, s1 = 0.f, s2 = 0.f, s3 = 0.f;
  for (int d = 0; d < D; ++d) {
    float wp = Wp[k * D + d], wc = Wc[k * D + d];
    s0 += wp * asp[d]; s1 += wp * adp[d];
    s2 += wc * asc[d]; s3 += wc * adc[d];
  }
  v[k] = s0; v[D + k] = s1; v[2 * D + k] = s2; v[3 * D + k] = s3;
}

// per-node attention scalars: a_* = emb[n] . v_*   (one wave per node)
__global__ void k_a(const float* __restrict__ emb, const float* __restrict__ v,
                    float* __restrict__ a_sp, float* __restrict__ a_dp,
                    float* __restrict__ a_sc, float* __restrict__ a_dc, int N) {
  int gtid = blockIdx.x * blockDim.x + threadIdx.x;
  int node = gtid >> 6;
  int lane = threadIdx.x & 63;
  if (node >= N) return;
  float2 x2 = ((const float2*)(emb + (size_t)node * D))[lane];
  float2 v0 = ((const float2*)(v))[lane];
  float2 v1 = ((const float2*)(v + D))[lane];
  float2 v2 = ((const float2*)(v + 2 * D))[lane];
  float2 v3 = ((const float2*)(v + 3 * D))[lane];
  float s0 = x2.x * v0.x + x2.y * v0.y;
  float s1 = x2.x * v1.x + x2.y * v1.y;
  float s2 = x2.x * v2.x + x2.y * v2.y;
  float s3 = x2.x * v3.x + x2.y * v3.y;
  for (int o = 32; o > 0; o >>= 1) {
    s0 += __shfl_down(s0, o);
    s1 += __shfl_down(s1, o);
    s2 += __shfl_down(s2, o);
    s3 += __shfl_down(s3, o);
  }
  if (lane == 0) { a_sp[node] = s0; a_dp[node] = s1; a_sc[node] = s2; a_dc[node] = s3; }
}

// H = X @ W, 16 rows per block, thread d owns output column d
__global__ void __launch_bounds__(128) k_matmul(const float* __restrict__ X,
                                                const float* __restrict__ W,
                                                float* __restrict__ H, int N) {
  const int NPB = 16;
  int d = threadIdx.x;
  int n0 = blockIdx.x * NPB;
  const float* xb[NPB];
#pragma unroll
  for (int j = 0; j < NPB; ++j) {
    int n = n0 + j;
    if (n >= N) n = N - 1;
    xb[j] = X + (size_t)n * D;
  }
  float acc[NPB];
#pragma unroll
  for (int j = 0; j < NPB; ++j) acc[j] = 0.f;
  for (int k = 0; k < D; ++k) {
    float w = W[k * D + d];
#pragma unroll
    for (int j = 0; j < NPB; ++j) acc[j] += xb[j][k] * w;
  }
#pragma unroll
  for (int j = 0; j < NPB; ++j) {
    int n = n0 + j;
    if (n < N) H[(size_t)n * D + d] = acc[j];
  }
}

// filter edges with queried dst; w = exp(leaky_relu(a_src+a_dst)); den[u] += w
__global__ void k_gat_filter(const int* __restrict__ ei, const float* __restrict__ a_s,
                             const float* __restrict__ a_d, const int* __restrict__ qid,
                             int2* __restrict__ lsu, float* __restrict__ lw,
                             float* __restrict__ den, int* __restrict__ cnt, int E) {
  int e = blockIdx.x * blockDim.x + threadIdx.x;
  if (e >= E) return;
  int dst = ei[E + e];
  int u = qid[dst];
  if (u < 0) return;
  int src = ei[e];
  float t = a_s[src] + a_d[dst];
  t = t >= 0.f ? t : 0.2f * t;
  float w = __expf(t);
  atomicAdd(&den[u], w);
  int p = atomicAdd(cnt, 1);
  int2 su; su.x = src; su.y = u;
  lsu[p] = su;
  lw[p] = w;
}

// num[u] += w * H[src]   (one wave per compact edge, grid-stride)
__global__ void k_gat_accum(const int2* __restrict__ lsu, const float* __restrict__ lw,
                            const float* __restrict__ H, float* __restrict__ num,
                            const int* __restrict__ cnt) {
  int gtid = blockIdx.x * blockDim.x + threadIdx.x;
  int wid = gtid >> 6;
  int lane = threadIdx.x & 63;
  int nw = (gridDim.x * blockDim.x) >> 6;
  int n = *cnt;
  for (int e = wid; e < n; e += nw) {
    int2 su = lsu[e];
    float w = lw[e];
    float2 h2 = ((const float2*)(H + (size_t)su.x * D))[lane];
    float* np = num + (size_t)su.y * D + 2 * lane;
    atomicAdd(np, w * h2.x);
    atomicAdd(np + 1, w * h2.y);
  }
}

// out row = (num + w_self*H[n]) / (den + w_self) + bias
__global__ void __launch_bounds__(128) k_gat_final(const float* __restrict__ num,
                            const float* __restrict__ den, const float* __restrict__ H,
                            const int* __restrict__ uniq, const int* __restrict__ counters,
                            const float* __restrict__ a_s, const float* __restrict__ a_d,
                            const float* __restrict__ bias, float* __restrict__ outU, int add) {
  int u = blockIdx.x;
  if (u >= counters[0]) return;
  int n = uniq[u];
  float t = a_s[n] + a_d[n];
  t = t >= 0.f ? t : 0.2f * t;
  float w = __expf(t);
  float dnm = den[u] + w;
  int d = threadIdx.x;
  float val = (num[(size_t)u * D + d] + w * H[(size_t)n * D + d]) / dnm + bias[d];
  size_t o = (size_t)u * D + d;
  if (add) outU[o] += val; else outU[o] = val;
}

__global__ void k_sage_filter(const int* __restrict__ ei, const int* __restrict__ qid,
                              int2* __restrict__ lsu, int* __restrict__ deg,
                              int* __restrict__ cnt, int E) {
  int e = blockIdx.x * blockDim.x + threadIdx.x;
  if (e >= E) return;
  int dst = ei[E + e];
  int u = qid[dst];
  if (u < 0) return;
  int src = ei[e];
  atomicAdd(&deg[u], 1);
  int p = atomicAdd(cnt, 1);
  int2 su; su.x = src; su.y = u;
  lsu[p] = su;
}

__global__ void k_sage_accum(const int2* __restrict__ lsu, const float* __restrict__ emb,
                             float* __restrict__ sum_r, const int* __restrict__ cnt) {
  int gtid = blockIdx.x * blockDim.x + threadIdx.x;
  int wid = gtid >> 6;
  int lane = threadIdx.x & 63;
  int nw = (gridDim.x * blockDim.x) >> 6;
  int n = *cnt;
  for (int e = wid; e < n; e += nw) {
    int2 su = lsu[e];
    float2 x2 = ((const float2*)(emb + (size_t)su.x * D))[lane];
    float* sp = sum_r + (size_t)su.y * D + 2 * lane;
    atomicAdd(sp, x2.x);
    atomicAdd(sp + 1, x2.y);
  }
}

// sum_r -> agg (divide by max(deg,1)) in place
__global__ void k_scale(float* __restrict__ sum_r, const int* __restrict__ deg,
                        const int* __restrict__ counters, int S) {
  int idx = blockIdx.x * blockDim.x + threadIdx.x;
  if (idx >= S * D) return;
  int u = idx >> 7;
  if (u >= counters[0]) return;
  float dg = (float)deg[u];
  if (dg < 1.f) dg = 1.f;
  sum_r[idx] = sum_r[idx] / dg;
}

// outU += agg@Wl + bl + emb[n]@Wr   (16 u per block, register tiled)
__global__ void __launch_bounds__(128) k_sage_final(const float* __restrict__ agg,
        const float* __restrict__ emb, const int* __restrict__ uniq,
        const int* __restrict__ counters, const float* __restrict__ Wl,
        const float* __restrict__ bl, const float* __restrict__ Wr,
        float* __restrict__ outU) {
  const int NPB = 16;
  int U = counters[0];
  int u0 = blockIdx.x * NPB;
  if (u0 >= U) return;
  int d = threadIdx.x;
  float acc[NPB];
#pragma unroll
  for (int j = 0; j < NPB; ++j) acc[j] = 0.f;
  const float* agg0 = agg + (size_t)u0 * D;
  const float* xb[NPB];
#pragma unroll
  for (int j = 0; j < NPB; ++j) {
    int u = u0 + j;
    int n = (u < U) ? uniq[u] : 0;
    xb[j] = emb + (size_t)n * D;
  }
  for (int k = 0; k < D; ++k) {
    float wl = Wl[k * D + d];
    float wr = Wr[k * D + d];
#pragma unroll
    for (int j = 0; j < NPB; ++j) acc[j] += agg0[j * D + k] * wl + xb[j][k] * wr;
  }
  float b = bl[d];
#pragma unroll
  for (int j = 0; j < NPB; ++j) {
    int u = u0 + j;
    if (u < U) outU[(size_t)u * D + d] += acc[j] + b;
  }
}

__global__ void k_gather(const int* __restrict__ s, const int* __restrict__ qid,
                         const float* __restrict__ outU, float* __restrict__ out, int S) {
  int idx = blockIdx.x * blockDim.x + threadIdx.x;
  if (idx >= S * D) return;
  int i = idx >> 7;
  int d = idx & (D - 1);
  int u = qid[s[i]];
  out[idx] = outU[(size_t)u * D + d] * (1.f / 3.f);
}

// ---------------- launch ----------------

extern "C" void kernel_launch(void* const* d_in, const int* in_sizes, int n_in,
                              void* d_out, int out_size, void* d_ws, size_t ws_size,
                              hipStream_t stream) {
  const int*   s   = (const int*)d_in[0];
  const int*   eip = (const int*)d_in[3];
  const int*   eic = (const int*)d_in[4];
  const int*   eir = (const int*)d_in[5];
  const float* emb = (const float*)d_in[6];
  const float* Wp  = (const float*)d_in[7];
  const float* asp = (const float*)d_in[8];
  const float* adp = (const float*)d_in[9];
  const float* bp  = (const float*)d_in[10];
  const float* Wc  = (const float*)d_in[11];
  const float* asc = (const float*)d_in[12];
  const float* adc = (const float*)d_in[13];
  const float* bc  = (const float*)d_in[14];
  const float* Wl  = (const float*)d_in[15];
  const float* bl  = (const float*)d_in[16];
  const float* Wr  = (const float*)d_in[17];
  float* out = (float*)d_out;

  const int S = in_sizes[0];
  const int E = in_sizes[3] / 2;
  const int N = in_sizes[6] / D;

  char* base = (char*)d_ws;
  size_t off = 0;
  auto carve = [&](size_t bytes) -> char* {
    char* q = base + off;
    off += (bytes + 255) & ~(size_t)255;
    return q;
  };
  float* H        = (float*)carve((size_t)N * D * 4);   // shared by parent then child GAT
  float* a_sp     = (float*)carve((size_t)N * 4);
  float* a_dp     = (float*)carve((size_t)N * 4);
  float* a_sc     = (float*)carve((size_t)N * 4);
  float* a_dc     = (float*)carve((size_t)N * 4);
  int*   qid      = (int*)carve((size_t)N * 4);
  int*   uniq     = (int*)carve((size_t)S * 4);
  int*   counters = (int*)carve(64);                    // [0]=U [1]=cntP [2]=cntC [3]=cntR
  float* vvec     = (float*)carve(4 * D * 4);
  float* num_p    = (float*)carve((size_t)S * D * 4);
  float* den_p    = (float*)carve((size_t)S * 4);
  float* num_c    = (float*)carve((size_t)S * D * 4);
  float* den_c    = (float*)carve((size_t)S * 4);
  float* sum_r    = (float*)carve((size_t)S * D * 4);
  int*   deg_r    = (int*)carve((size_t)S * 4);
  float* outU     = (float*)carve((size_t)S * D * 4);
  int2*  lsu      = (int2*)carve((size_t)E * 8);        // reused parent/child
  float* lw       = (float*)carve((size_t)E * 4);
  int2*  lsuR     = (int2*)carve((size_t)E * 8);
  (void)ws_size; (void)n_in; (void)out_size;

  // zero-init (d_ws is poisoned 0xAA before every timed launch)
  hipMemsetAsync(qid, 0xFF, (size_t)N * 4, stream);     // -1
  hipMemsetAsync(counters, 0, 64, stream);
  hipMemsetAsync(num_p, 0, (size_t)S * D * 4, stream);
  hipMemsetAsync(den_p, 0, (size_t)S * 4, stream);
  hipMemsetAsync(num_c, 0, (size_t)S * D * 4, stream);
  hipMemsetAsync(den_c, 0, (size_t)S * 4, stream);
  hipMemsetAsync(sum_r, 0, (size_t)S * D * 4, stream);
  hipMemsetAsync(deg_r, 0, (size_t)S * 4, stream);

  k_build_qid<<<(S + 255) / 256, 256, 0, stream>>>(s, qid, uniq, counters, S);
  k_calc_v<<<1, 128, 0, stream>>>(Wp, asp, adp, Wc, asc, adc, vvec);
  k_a<<<(N + 3) / 4, 256, 0, stream>>>(emb, vvec, a_sp, a_dp, a_sc, a_dc, N);

  // SAGE relation (independent of H)
  k_sage_filter<<<(E + 255) / 256, 256, 0, stream>>>(eir, qid, lsuR, deg_r, counters + 3, E);
  k_sage_accum<<<1024, 256, 0, stream>>>(lsuR, emb, sum_r, counters + 3);
  k_scale<<<(S * D + 255) / 256, 256, 0, stream>>>(sum_r, deg_r, counters, S);

  // GAT parent
  k_matmul<<<(N + 15) / 16, 128, 0, stream>>>(emb, Wp, H, N);
  k_gat_filter<<<(E + 255) / 256, 256, 0, stream>>>(eip, a_sp, a_dp, qid, lsu, lw, den_p, counters + 1, E);
  k_gat_accum<<<1024, 256, 0, stream>>>(lsu, lw, H, num_p, counters + 1);
  k_gat_final<<<S, 128, 0, stream>>>(num_p, den_p, H, uniq, counters, a_sp, a_dp, bp, outU, 0);

  // GAT child (H reused)
  k_matmul<<<(N + 15) / 16, 128, 0, stream>>>(emb, Wc, H, N);
  k_gat_filter<<<(E + 255) / 256, 256, 0, stream>>>(eic, a_sc, a_dc, qid, lsu, lw, den_c, counters + 2, E);
  k_gat_accum<<<1024, 256, 0, stream>>>(lsu, lw, H, num_c, counters + 2);
  k_gat_final<<<S, 128, 0, stream>>>(num_c, den_c, H, uniq, counters, a_sc, a_dc, bc, outU, 1);

  // SAGE final + gather
  k_sage_final<<<(S + 15) / 16, 128, 0, stream>>>(sum_r, emb, uniq, counters, Wl, bl, Wr, outU);
  k_gather<<<(S * D + 255) / 256, 256, 0, stream>>>(s, qid, outU, out, S);
}

// Round 2
// 713.607 us; speedup vs baseline: 1.6895x; 1.6895x over previous
//
#include <hip/hip_runtime.h>

#define D 128

// ---------------- kernels ----------------

__global__ void k_build_qid(const int* __restrict__ s, int* __restrict__ qid,
                            int* __restrict__ uniq, int* __restrict__ counters, int S) {
  int i = blockIdx.x * blockDim.x + threadIdx.x;
  if (i >= S) return;
  int n = s[i];
  if (atomicCAS(&qid[n], -1, -2) == -1) {
    int u = atomicAdd(&counters[0], 1);
    uniq[u] = n;
    qid[n] = u;   // visible to later kernels (kernel boundary)
  }
}

// v = [Wp@asp, Wp@adp, Wc@asc, Wc@adc, bp+bc+bl]
__global__ void k_calc_v(const float* __restrict__ Wp, const float* __restrict__ asp,
                         const float* __restrict__ adp, const float* __restrict__ Wc,
                         const float* __restrict__ asc, const float* __restrict__ adc,
                         const float* __restrict__ bp, const float* __restrict__ bc,
                         const float* __restrict__ bl, float* __restrict__ v) {
  int k = threadIdx.x;  // 0..127
  float s0 = 0.f, s1 = 0.f, s2 = 0.f, s3 = 0.f;
  for (int d = 0; d < D; ++d) {
    float wp = Wp[k * D + d], wc = Wc[k * D + d];
    s0 += wp * asp[d]; s1 += wp * adp[d];
    s2 += wc * asc[d]; s3 += wc * adc[d];
  }
  v[k] = s0; v[D + k] = s1; v[2 * D + k] = s2; v[3 * D + k] = s3;
  v[4 * D + k] = bp[k] + bc[k] + bl[k];
}

// per-node attention scalars: a_* = emb[n] . v_*   (one wave per node)
__global__ void k_a(const float* __restrict__ emb, const float* __restrict__ v,
                    float* __restrict__ a_sp, float* __restrict__ a_dp,
                    float* __restrict__ a_sc, float* __restrict__ a_dc, int N) {
  int gtid = blockIdx.x * blockDim.x + threadIdx.x;
  int node = gtid >> 6;
  int lane = threadIdx.x & 63;
  if (node >= N) return;
  float2 x2 = ((const float2*)(emb + (size_t)node * D))[lane];
  float2 v0 = ((const float2*)(v))[lane];
  float2 v1 = ((const float2*)(v + D))[lane];
  float2 v2 = ((const float2*)(v + 2 * D))[lane];
  float2 v3 = ((const float2*)(v + 3 * D))[lane];
  float s0 = x2.x * v0.x + x2.y * v0.y;
  float s1 = x2.x * v1.x + x2.y * v1.y;
  float s2 = x2.x * v2.x + x2.y * v2.y;
  float s3 = x2.x * v3.x + x2.y * v3.y;
  for (int o = 32; o > 0; o >>= 1) {
    s0 += __shfl_down(s0, o);
    s1 += __shfl_down(s1, o);
    s2 += __shfl_down(s2, o);
    s3 += __shfl_down(s3, o);
  }
  if (lane == 0) { a_sp[node] = s0; a_dp[node] = s1; a_sc[node] = s2; a_dc[node] = s3; }
}

// filter edges with queried dst; w = exp(leaky_relu(a_src+a_dst)); den[u] += w
__global__ void k_gat_filter(const int* __restrict__ ei, const float* __restrict__ a_s,
                             const float* __restrict__ a_d, const int* __restrict__ qid,
                             int2* __restrict__ lsu, float* __restrict__ lw,
                             float* __restrict__ den, int* __restrict__ cnt, int E) {
  int e = blockIdx.x * blockDim.x + threadIdx.x;
  if (e >= E) return;
  int dst = ei[E + e];
  int u = qid[dst];
  if (u < 0) return;
  int src = ei[e];
  float t = a_s[src] + a_d[dst];
  t = t >= 0.f ? t : 0.2f * t;
  float w = __expf(t);
  atomicAdd(&den[u], w);
  int p = atomicAdd(cnt, 1);
  int2 su; su.x = src; su.y = u;
  lsu[p] = su;
  lw[p] = w;
}

// num[u] += w * emb[src]   (one wave per compact edge, grid-stride)
__global__ void k_gat_accum(const int2* __restrict__ lsu, const float* __restrict__ lw,
                            const float* __restrict__ x, float* __restrict__ num,
                            const int* __restrict__ cnt) {
  int gtid = blockIdx.x * blockDim.x + threadIdx.x;
  int wid = gtid >> 6;
  int lane = threadIdx.x & 63;
  int nw = (gridDim.x * blockDim.x) >> 6;
  int n = *cnt;
  for (int e = wid; e < n; e += nw) {
    int2 su = lsu[e];
    float w = lw[e];
    float2 h2 = ((const float2*)(x + (size_t)su.x * D))[lane];
    float* np = num + (size_t)su.y * D + 2 * lane;
    atomicAdd(np, w * h2.x);
    atomicAdd(np + 1, w * h2.y);
  }
}

__global__ void k_sage_filter(const int* __restrict__ ei, const int* __restrict__ qid,
                              int2* __restrict__ lsu, int* __restrict__ deg,
                              int* __restrict__ cnt, int E) {
  int e = blockIdx.x * blockDim.x + threadIdx.x;
  if (e >= E) return;
  int dst = ei[E + e];
  int u = qid[dst];
  if (u < 0) return;
  int src = ei[e];
  atomicAdd(&deg[u], 1);
  int p = atomicAdd(cnt, 1);
  int2 su; su.x = src; su.y = u;
  lsu[p] = su;
}

__global__ void k_sage_accum(const int2* __restrict__ lsu, const float* __restrict__ emb,
                             float* __restrict__ sum_r, const int* __restrict__ cnt) {
  int gtid = blockIdx.x * blockDim.x + threadIdx.x;
  int wid = gtid >> 6;
  int lane = threadIdx.x & 63;
  int nw = (gridDim.x * blockDim.x) >> 6;
  int n = *cnt;
  for (int e = wid; e < n; e += nw) {
    int2 su = lsu[e];
    float2 x2 = ((const float2*)(emb + (size_t)su.x * D))[lane];
    float* sp = sum_r + (size_t)su.y * D + 2 * lane;
    atomicAdd(sp, x2.x);
    atomicAdd(sp + 1, x2.y);
  }
}

// per-u scalars: [wP, 1/(denP+wP), wC, 1/(denC+wC), 1/max(deg,1), 0,0,0]
__global__ void k_scalars(const int* __restrict__ uniq, const int* __restrict__ counters,
                          const float* __restrict__ a_sp, const float* __restrict__ a_dp,
                          const float* __restrict__ a_sc, const float* __restrict__ a_dc,
                          const float* __restrict__ den_p, const float* __restrict__ den_c,
                          const int* __restrict__ deg_r, float* __restrict__ scal) {
  int u = blockIdx.x * blockDim.x + threadIdx.x;
  if (u >= counters[0]) return;
  int n = uniq[u];
  float tP = a_sp[n] + a_dp[n]; tP = tP >= 0.f ? tP : 0.2f * tP;
  float wP = __expf(tP);
  float tC = a_sc[n] + a_dc[n]; tC = tC >= 0.f ? tC : 0.2f * tC;
  float wC = __expf(tC);
  float dg = (float)deg_r[u]; if (dg < 1.f) dg = 1.f;
  float* sc = scal + (size_t)u * 8;
  sc[0] = wP; sc[1] = 1.f / (den_p[u] + wP);
  sc[2] = wC; sc[3] = 1.f / (den_c[u] + wC);
  sc[4] = 1.f / dg;
}

// fused final: outU[u] = aggP@Wp + aggC@Wc + aggR@Wl + emb[n]@Wr
// 16 u-rows per block; wave o owns matrix o; thread owns 2 columns.
__global__ void __launch_bounds__(256) k_final(
    const float* __restrict__ num_p, const float* __restrict__ num_c,
    const float* __restrict__ sum_r, const float* __restrict__ emb,
    const int* __restrict__ uniq, const int* __restrict__ counters,
    const float* __restrict__ scal,
    const float* __restrict__ Wp, const float* __restrict__ Wc,
    const float* __restrict__ Wl, const float* __restrict__ Wr,
    float* __restrict__ outU) {
  __shared__ float zs[4][16][D];   // 32 KB: z-rows then partial sums
  int U = counters[0];
  int u0 = blockIdx.x * 16;
  if (u0 >= U) return;
  int tid = threadIdx.x;

  // stage z-rows: z0=(num_p+wP*x)/denP  z1=(num_c+wC*x)/denC  z2=sum_r/deg  z3=x
  for (int t = tid; t < 512; t += 256) {
    int j = t >> 5;
    int c4 = (t & 31) * 4;
    int u = u0 + j;
    int uu = (u < U) ? u : u0;
    int n = uniq[uu];
    const float* sc = scal + (size_t)uu * 8;
    float wP = sc[0], rP = sc[1], wC = sc[2], rC = sc[3], rdeg = sc[4];
    float4 e4  = *(const float4*)(emb   + (size_t)n  * D + c4);
    float4 np4 = *(const float4*)(num_p + (size_t)uu * D + c4);
    float4 nc4 = *(const float4*)(num_c + (size_t)uu * D + c4);
    float4 sr4 = *(const float4*)(sum_r + (size_t)uu * D + c4);
    float4 z0, z1, z2;
    z0.x = (np4.x + wP * e4.x) * rP; z0.y = (np4.y + wP * e4.y) * rP;
    z0.z = (np4.z + wP * e4.z) * rP; z0.w = (np4.w + wP * e4.w) * rP;
    z1.x = (nc4.x + wC * e4.x) * rC; z1.y = (nc4.y + wC * e4.y) * rC;
    z1.z = (nc4.z + wC * e4.z) * rC; z1.w = (nc4.w + wC * e4.w) * rC;
    z2.x = sr4.x * rdeg; z2.y = sr4.y * rdeg; z2.z = sr4.z * rdeg; z2.w = sr4.w * rdeg;
    *(float4*)&zs[0][j][c4] = z0;
    *(float4*)&zs[1][j][c4] = z1;
    *(float4*)&zs[2][j][c4] = z2;
    *(float4*)&zs[3][j][c4] = e4;
  }
  __syncthreads();

  int o = tid >> 6;        // wave id == operand
  int lane = tid & 63;
  int c0 = lane, c1 = lane + 64;
  const float* W = (o == 0) ? Wp : (o == 1) ? Wc : (o == 2) ? Wl : Wr;

  float acc0[16], acc1[16];
#pragma unroll
  for (int j = 0; j < 16; ++j) { acc0[j] = 0.f; acc1[j] = 0.f; }

  float wcur[8], wnext[8];
#pragma unroll
  for (int kk = 0; kk < 4; ++kk) {
    wcur[kk]     = W[kk * D + c0];
    wcur[4 + kk] = W[kk * D + c1];
  }
  for (int c = 0; c < 32; ++c) {
    int kb = c * 4;
    if (c < 31) {
#pragma unroll
      for (int kk = 0; kk < 4; ++kk) {
        wnext[kk]     = W[(kb + 4 + kk) * D + c0];
        wnext[4 + kk] = W[(kb + 4 + kk) * D + c1];
      }
    }
#pragma unroll
    for (int j = 0; j < 16; ++j) {
      float4 v = *(const float4*)&zs[o][j][kb];
      acc0[j] += v.x * wcur[0] + v.y * wcur[1] + v.z * wcur[2] + v.w * wcur[3];
      acc1[j] += v.x * wcur[4] + v.y * wcur[5] + v.z * wcur[6] + v.w * wcur[7];
    }
#pragma unroll
    for (int kk = 0; kk < 8; ++kk) wcur[kk] = wnext[kk];
  }
  __syncthreads();

  // write partials, reduce across the 4 operand waves
#pragma unroll
  for (int j = 0; j < 16; ++j) {
    zs[o][j][c0] = acc0[j];
    zs[o][j][c1] = acc1[j];
  }
  __syncthreads();

  int col = tid & 127;
  int j0 = (tid >> 7) * 8;
#pragma unroll
  for (int jj = 0; jj < 8; ++jj) {
    int j = j0 + jj;
    int u = u0 + j;
    if (u < U) {
      float s = zs[0][j][col] + zs[1][j][col] + zs[2][j][col] + zs[3][j][col];
      outU[(size_t)u * D + col] = s;
    }
  }
}

__global__ void k_gather(const int* __restrict__ s, const int* __restrict__ qid,
                         const float* __restrict__ outU, const float* __restrict__ v,
                         float* __restrict__ out, int S) {
  int idx = blockIdx.x * blockDim.x + threadIdx.x;
  if (idx >= S * D) return;
  int i = idx >> 7;
  int d = idx & (D - 1);
  int u = qid[s[i]];
  out[idx] = (outU[(size_t)u * D + d] + v[4 * D + d]) * (1.f / 3.f);
}

// ---------------- launch ----------------

extern "C" void kernel_launch(void* const* d_in, const int* in_sizes, int n_in,
                              void* d_out, int out_size, void* d_ws, size_t ws_size,
                              hipStream_t stream) {
  const int*   s   = (const int*)d_in[0];
  const int*   eip = (const int*)d_in[3];
  const int*   eic = (const int*)d_in[4];
  const int*   eir = (const int*)d_in[5];
  const float* emb = (const float*)d_in[6];
  const float* Wp  = (const float*)d_in[7];
  const float* asp = (const float*)d_in[8];
  const float* adp = (const float*)d_in[9];
  const float* bp  = (const float*)d_in[10];
  const float* Wc  = (const float*)d_in[11];
  const float* asc = (const float*)d_in[12];
  const float* adc = (const float*)d_in[13];
  const float* bc  = (const float*)d_in[14];
  const float* Wl  = (const float*)d_in[15];
  const float* bl  = (const float*)d_in[16];
  const float* Wr  = (const float*)d_in[17];
  float* out = (float*)d_out;

  const int S = in_sizes[0];
  const int E = in_sizes[3] / 2;
  const int N = in_sizes[6] / D;

  char* base = (char*)d_ws;
  size_t off = 0;
  auto carve = [&](size_t bytes) -> char* {
    char* q = base + off;
    off += (bytes + 255) & ~(size_t)255;
    return q;
  };
  float* a_sp     = (float*)carve((size_t)N * 4);
  float* a_dp     = (float*)carve((size_t)N * 4);
  float* a_sc     = (float*)carve((size_t)N * 4);
  float* a_dc     = (float*)carve((size_t)N * 4);
  int*   qid      = (int*)carve((size_t)N * 4);
  int*   uniq     = (int*)carve((size_t)S * 4);
  int*   counters = (int*)carve(64);                    // [0]=U [1]=cntP [2]=cntC [3]=cntR
  float* vvec     = (float*)carve(5 * D * 4);
  float* num_p    = (float*)carve((size_t)S * D * 4);
  float* den_p    = (float*)carve((size_t)S * 4);
  float* num_c    = (float*)carve((size_t)S * D * 4);
  float* den_c    = (float*)carve((size_t)S * 4);
  float* sum_r    = (float*)carve((size_t)S * D * 4);
  int*   deg_r    = (int*)carve((size_t)S * 4);
  float* outU     = (float*)carve((size_t)S * D * 4);
  float* scal     = (float*)carve((size_t)S * 8 * 4);
  int2*  lsu      = (int2*)carve((size_t)E * 8);        // reused parent/child
  float* lw       = (float*)carve((size_t)E * 4);
  int2*  lsuR     = (int2*)carve((size_t)E * 8);
  (void)ws_size; (void)n_in; (void)out_size;

  // zero-init (d_ws is poisoned 0xAA before every timed launch)
  hipMemsetAsync(qid, 0xFF, (size_t)N * 4, stream);     // -1
  hipMemsetAsync(counters, 0, 64, stream);
  hipMemsetAsync(num_p, 0, (size_t)S * D * 4, stream);
  hipMemsetAsync(den_p, 0, (size_t)S * 4, stream);
  hipMemsetAsync(num_c, 0, (size_t)S * D * 4, stream);
  hipMemsetAsync(den_c, 0, (size_t)S * 4, stream);
  hipMemsetAsync(sum_r, 0, (size_t)S * D * 4, stream);
  hipMemsetAsync(deg_r, 0, (size_t)S * 4, stream);

  k_build_qid<<<(S + 255) / 256, 256, 0, stream>>>(s, qid, uniq, counters, S);
  k_calc_v<<<1, 128, 0, stream>>>(Wp, asp, adp, Wc, asc, adc, bp, bc, bl, vvec);
  k_a<<<(N + 3) / 4, 256, 0, stream>>>(emb, vvec, a_sp, a_dp, a_sc, a_dc, N);

  // edge filtering + raw-emb aggregation (W applied later, only on U rows)
  k_sage_filter<<<(E + 255) / 256, 256, 0, stream>>>(eir, qid, lsuR, deg_r, counters + 3, E);
  k_sage_accum<<<1024, 256, 0, stream>>>(lsuR, emb, sum_r, counters + 3);

  k_gat_filter<<<(E + 255) / 256, 256, 0, stream>>>(eip, a_sp, a_dp, qid, lsu, lw, den_p, counters + 1, E);
  k_gat_accum<<<1024, 256, 0, stream>>>(lsu, lw, emb, num_p, counters + 1);

  k_gat_filter<<<(E + 255) / 256, 256, 0, stream>>>(eic, a_sc, a_dc, qid, lsu, lw, den_c, counters + 2, E);
  k_gat_accum<<<1024, 256, 0, stream>>>(lsu, lw, emb, num_c, counters + 2);

  k_scalars<<<(S + 255) / 256, 256, 0, stream>>>(uniq, counters, a_sp, a_dp, a_sc, a_dc,
                                                 den_p, den_c, deg_r, scal);
  k_final<<<(S + 15) / 16, 256, 0, stream>>>(num_p, num_c, sum_r, emb, uniq, counters,
                                             scal, Wp, Wc, Wl, Wr, outU);
  k_gather<<<(S * D + 255) / 256, 256, 0, stream>>>(s, qid, outU, vvec, out, S);
}

// Round 3
// 462.010 us; speedup vs baseline: 2.6096x; 1.5446x over previous
//
#include <hip/hip_runtime.h>

#define D 128

// ---------------- kernels ----------------

__global__ void k_build_qid(const int* __restrict__ s, int* __restrict__ qid,
                            int* __restrict__ uniq, int* __restrict__ counters, int S) {
  int i = blockIdx.x * blockDim.x + threadIdx.x;
  if (i >= S) return;
  int n = s[i];
  if (atomicCAS(&qid[n], -1, -2) == -1) {
    int u = atomicAdd(&counters[0], 1);
    uniq[u] = n;
    qid[n] = u;   // visible to later kernels (kernel boundary)
  }
}

// v = [Wp@asp, Wp@adp, Wc@asc, Wc@adc, bp+bc+bl]
__global__ void k_calc_v(const float* __restrict__ Wp, const float* __restrict__ asp,
                         const float* __restrict__ adp, const float* __restrict__ Wc,
                         const float* __restrict__ asc, const float* __restrict__ adc,
                         const float* __restrict__ bp, const float* __restrict__ bc,
                         const float* __restrict__ bl, float* __restrict__ v) {
  int k = threadIdx.x;  // 0..127
  float s0 = 0.f, s1 = 0.f, s2 = 0.f, s3 = 0.f;
  for (int d = 0; d < D; ++d) {
    float wp = Wp[k * D + d], wc = Wc[k * D + d];
    s0 += wp * asp[d]; s1 += wp * adp[d];
    s2 += wc * asc[d]; s3 += wc * adc[d];
  }
  v[k] = s0; v[D + k] = s1; v[2 * D + k] = s2; v[3 * D + k] = s3;
  v[4 * D + k] = bp[k] + bc[k] + bl[k];
}

// per-node attention scalars: a_* = emb[n] . v_*   (one wave per node)
__global__ void k_a(const float* __restrict__ emb, const float* __restrict__ v,
                    float* __restrict__ a_sp, float* __restrict__ a_dp,
                    float* __restrict__ a_sc, float* __restrict__ a_dc, int N) {
  int gtid = blockIdx.x * blockDim.x + threadIdx.x;
  int node = gtid >> 6;
  int lane = threadIdx.x & 63;
  if (node >= N) return;
  float2 x2 = ((const float2*)(emb + (size_t)node * D))[lane];
  float2 v0 = ((const float2*)(v))[lane];
  float2 v1 = ((const float2*)(v + D))[lane];
  float2 v2 = ((const float2*)(v + 2 * D))[lane];
  float2 v3 = ((const float2*)(v + 3 * D))[lane];
  float s0 = x2.x * v0.x + x2.y * v0.y;
  float s1 = x2.x * v1.x + x2.y * v1.y;
  float s2 = x2.x * v2.x + x2.y * v2.y;
  float s3 = x2.x * v3.x + x2.y * v3.y;
  for (int o = 32; o > 0; o >>= 1) {
    s0 += __shfl_down(s0, o);
    s1 += __shfl_down(s1, o);
    s2 += __shfl_down(s2, o);
    s3 += __shfl_down(s3, o);
  }
  if (lane == 0) { a_sp[node] = s0; a_dp[node] = s1; a_sc[node] = s2; a_dc[node] = s3; }
}

// filter edges with queried dst; block-aggregated compaction (ONE atomic per block)
__global__ void __launch_bounds__(1024) k_gat_filter(
    const int* __restrict__ ei, const float* __restrict__ a_s,
    const float* __restrict__ a_d, const int* __restrict__ qid,
    int2* __restrict__ lsu, float* __restrict__ lw,
    float* __restrict__ den, int* __restrict__ cnt, int E) {
  int e = blockIdx.x * 1024 + threadIdx.x;
  bool active = false;
  int src = 0, u = 0; float w = 0.f;
  if (e < E) {
    int dst = ei[E + e];
    u = qid[dst];
    if (u >= 0) {
      src = ei[e];
      float t = a_s[src] + a_d[dst];
      t = t >= 0.f ? t : 0.2f * t;
      w = __expf(t);
      active = true;
    }
  }
  unsigned long long mask = __ballot(active);
  int lane = threadIdx.x & 63;
  int wid = threadIdx.x >> 6;           // 0..15
  __shared__ int wbase[16];
  if (lane == 0) wbase[wid] = __popcll(mask);
  __syncthreads();
  if (threadIdx.x == 0) {
    int tot = 0, pref[16];
#pragma unroll
    for (int i = 0; i < 16; ++i) { pref[i] = tot; tot += wbase[i]; }
    int b = atomicAdd(cnt, tot);
#pragma unroll
    for (int i = 0; i < 16; ++i) wbase[i] = b + pref[i];
  }
  __syncthreads();
  if (active) {
    int pos = wbase[wid] + __popcll(mask & ((1ULL << lane) - 1));
    int2 su; su.x = src; su.y = u;
    lsu[pos] = su;
    lw[pos] = w;
    atomicAdd(&den[u], w);
  }
}

__global__ void __launch_bounds__(1024) k_sage_filter(
    const int* __restrict__ ei, const int* __restrict__ qid,
    int2* __restrict__ lsu, int* __restrict__ deg,
    int* __restrict__ cnt, int E) {
  int e = blockIdx.x * 1024 + threadIdx.x;
  bool active = false;
  int src = 0, u = 0;
  if (e < E) {
    int dst = ei[E + e];
    u = qid[dst];
    if (u >= 0) { src = ei[e]; active = true; }
  }
  unsigned long long mask = __ballot(active);
  int lane = threadIdx.x & 63;
  int wid = threadIdx.x >> 6;
  __shared__ int wbase[16];
  if (lane == 0) wbase[wid] = __popcll(mask);
  __syncthreads();
  if (threadIdx.x == 0) {
    int tot = 0, pref[16];
#pragma unroll
    for (int i = 0; i < 16; ++i) { pref[i] = tot; tot += wbase[i]; }
    int b = atomicAdd(cnt, tot);
#pragma unroll
    for (int i = 0; i < 16; ++i) wbase[i] = b + pref[i];
  }
  __syncthreads();
  if (active) {
    int pos = wbase[wid] + __popcll(mask & ((1ULL << lane) - 1));
    int2 su; su.x = src; su.y = u;
    lsu[pos] = su;
    atomicAdd(&deg[u], 1);
  }
}

// num[u] += w * emb[src]   (one wave per compact edge, grid-stride)
__global__ void k_gat_accum(const int2* __restrict__ lsu, const float* __restrict__ lw,
                            const float* __restrict__ x, float* __restrict__ num,
                            const int* __restrict__ cnt) {
  int gtid = blockIdx.x * blockDim.x + threadIdx.x;
  int wid = gtid >> 6;
  int lane = threadIdx.x & 63;
  int nw = (gridDim.x * blockDim.x) >> 6;
  int n = *cnt;
  for (int e = wid; e < n; e += nw) {
    int2 su = lsu[e];
    float w = lw[e];
    float2 h2 = ((const float2*)(x + (size_t)su.x * D))[lane];
    float* np = num + (size_t)su.y * D + 2 * lane;
    atomicAdd(np, w * h2.x);
    atomicAdd(np + 1, w * h2.y);
  }
}

__global__ void k_sage_accum(const int2* __restrict__ lsu, const float* __restrict__ emb,
                             float* __restrict__ sum_r, const int* __restrict__ cnt) {
  int gtid = blockIdx.x * blockDim.x + threadIdx.x;
  int wid = gtid >> 6;
  int lane = threadIdx.x & 63;
  int nw = (gridDim.x * blockDim.x) >> 6;
  int n = *cnt;
  for (int e = wid; e < n; e += nw) {
    int2 su = lsu[e];
    float2 x2 = ((const float2*)(emb + (size_t)su.x * D))[lane];
    float* sp = sum_r + (size_t)su.y * D + 2 * lane;
    atomicAdd(sp, x2.x);
    atomicAdd(sp + 1, x2.y);
  }
}

// per-u scalars: [wP, 1/(denP+wP), wC, 1/(denC+wC), 1/max(deg,1), 0,0,0]
__global__ void k_scalars(const int* __restrict__ uniq, const int* __restrict__ counters,
                          const float* __restrict__ a_sp, const float* __restrict__ a_dp,
                          const float* __restrict__ a_sc, const float* __restrict__ a_dc,
                          const float* __restrict__ den_p, const float* __restrict__ den_c,
                          const int* __restrict__ deg_r, float* __restrict__ scal) {
  int u = blockIdx.x * blockDim.x + threadIdx.x;
  if (u >= counters[0]) return;
  int n = uniq[u];
  float tP = a_sp[n] + a_dp[n]; tP = tP >= 0.f ? tP : 0.2f * tP;
  float wP = __expf(tP);
  float tC = a_sc[n] + a_dc[n]; tC = tC >= 0.f ? tC : 0.2f * tC;
  float wC = __expf(tC);
  float dg = (float)deg_r[u]; if (dg < 1.f) dg = 1.f;
  float* sc = scal + (size_t)u * 8;
  sc[0] = wP; sc[1] = 1.f / (den_p[u] + wP);
  sc[2] = wC; sc[3] = 1.f / (den_c[u] + wC);
  sc[4] = 1.f / dg;
}

// fused final: outU[u] = aggP@Wp + aggC@Wc + aggR@Wl + emb[n]@Wr
// 16 u-rows per block; wave o owns matrix o; thread owns 2 columns.
__global__ void __launch_bounds__(256) k_final(
    const float* __restrict__ num_p, const float* __restrict__ num_c,
    const float* __restrict__ sum_r, const float* __restrict__ emb,
    const int* __restrict__ uniq, const int* __restrict__ counters,
    const float* __restrict__ scal,
    const float* __restrict__ Wp, const float* __restrict__ Wc,
    const float* __restrict__ Wl, const float* __restrict__ Wr,
    float* __restrict__ outU) {
  __shared__ float zs[4][16][D];   // 32 KB: z-rows then partial sums
  int U = counters[0];
  int u0 = blockIdx.x * 16;
  if (u0 >= U) return;
  int tid = threadIdx.x;

  // stage z-rows: z0=(num_p+wP*x)/denP  z1=(num_c+wC*x)/denC  z2=sum_r/deg  z3=x
  for (int t = tid; t < 512; t += 256) {
    int j = t >> 5;
    int c4 = (t & 31) * 4;
    int u = u0 + j;
    int uu = (u < U) ? u : u0;
    int n = uniq[uu];
    const float* sc = scal + (size_t)uu * 8;
    float wP = sc[0], rP = sc[1], wC = sc[2], rC = sc[3], rdeg = sc[4];
    float4 e4  = *(const float4*)(emb   + (size_t)n  * D + c4);
    float4 np4 = *(const float4*)(num_p + (size_t)uu * D + c4);
    float4 nc4 = *(const float4*)(num_c + (size_t)uu * D + c4);
    float4 sr4 = *(const float4*)(sum_r + (size_t)uu * D + c4);
    float4 z0, z1, z2;
    z0.x = (np4.x + wP * e4.x) * rP; z0.y = (np4.y + wP * e4.y) * rP;
    z0.z = (np4.z + wP * e4.z) * rP; z0.w = (np4.w + wP * e4.w) * rP;
    z1.x = (nc4.x + wC * e4.x) * rC; z1.y = (nc4.y + wC * e4.y) * rC;
    z1.z = (nc4.z + wC * e4.z) * rC; z1.w = (nc4.w + wC * e4.w) * rC;
    z2.x = sr4.x * rdeg; z2.y = sr4.y * rdeg; z2.z = sr4.z * rdeg; z2.w = sr4.w * rdeg;
    *(float4*)&zs[0][j][c4] = z0;
    *(float4*)&zs[1][j][c4] = z1;
    *(float4*)&zs[2][j][c4] = z2;
    *(float4*)&zs[3][j][c4] = e4;
  }
  __syncthreads();

  int o = tid >> 6;        // wave id == operand
  int lane = tid & 63;
  int c0 = lane, c1 = lane + 64;
  const float* W = (o == 0) ? Wp : (o == 1) ? Wc : (o == 2) ? Wl : Wr;

  float acc0[16], acc1[16];
#pragma unroll
  for (int j = 0; j < 16; ++j) { acc0[j] = 0.f; acc1[j] = 0.f; }

  float wcur[8], wnext[8];
#pragma unroll
  for (int kk = 0; kk < 4; ++kk) {
    wcur[kk]     = W[kk * D + c0];
    wcur[4 + kk] = W[kk * D + c1];
  }
  for (int c = 0; c < 32; ++c) {
    int kb = c * 4;
    if (c < 31) {
#pragma unroll
      for (int kk = 0; kk < 4; ++kk) {
        wnext[kk]     = W[(kb + 4 + kk) * D + c0];
        wnext[4 + kk] = W[(kb + 4 + kk) * D + c1];
      }
    }
#pragma unroll
    for (int j = 0; j < 16; ++j) {
      float4 v = *(const float4*)&zs[o][j][kb];
      acc0[j] += v.x * wcur[0] + v.y * wcur[1] + v.z * wcur[2] + v.w * wcur[3];
      acc1[j] += v.x * wcur[4] + v.y * wcur[5] + v.z * wcur[6] + v.w * wcur[7];
    }
#pragma unroll
    for (int kk = 0; kk < 8; ++kk) wcur[kk] = wnext[kk];
  }
  __syncthreads();

  // write partials, reduce across the 4 operand waves
#pragma unroll
  for (int j = 0; j < 16; ++j) {
    zs[o][j][c0] = acc0[j];
    zs[o][j][c1] = acc1[j];
  }
  __syncthreads();

  int col = tid & 127;
  int j0 = (tid >> 7) * 8;
#pragma unroll
  for (int jj = 0; jj < 8; ++jj) {
    int j = j0 + jj;
    int u = u0 + j;
    if (u < U) {
      float s = zs[0][j][col] + zs[1][j][col] + zs[2][j][col] + zs[3][j][col];
      outU[(size_t)u * D + col] = s;
    }
  }
}

__global__ void k_gather(const int* __restrict__ s, const int* __restrict__ qid,
                         const float* __restrict__ outU, const float* __restrict__ v,
                         float* __restrict__ out, int S) {
  int idx = blockIdx.x * blockDim.x + threadIdx.x;
  if (idx >= S * D) return;
  int i = idx >> 7;
  int d = idx & (D - 1);
  int u = qid[s[i]];
  out[idx] = (outU[(size_t)u * D + d] + v[4 * D + d]) * (1.f / 3.f);
}

// ---------------- launch ----------------

extern "C" void kernel_launch(void* const* d_in, const int* in_sizes, int n_in,
                              void* d_out, int out_size, void* d_ws, size_t ws_size,
                              hipStream_t stream) {
  const int*   s   = (const int*)d_in[0];
  const int*   eip = (const int*)d_in[3];
  const int*   eic = (const int*)d_in[4];
  const int*   eir = (const int*)d_in[5];
  const float* emb = (const float*)d_in[6];
  const float* Wp  = (const float*)d_in[7];
  const float* asp = (const float*)d_in[8];
  const float* adp = (const float*)d_in[9];
  const float* bp  = (const float*)d_in[10];
  const float* Wc  = (const float*)d_in[11];
  const float* asc = (const float*)d_in[12];
  const float* adc = (const float*)d_in[13];
  const float* bc  = (const float*)d_in[14];
  const float* Wl  = (const float*)d_in[15];
  const float* bl  = (const float*)d_in[16];
  const float* Wr  = (const float*)d_in[17];
  float* out = (float*)d_out;

  const int S = in_sizes[0];
  const int E = in_sizes[3] / 2;
  const int N = in_sizes[6] / D;

  char* base = (char*)d_ws;
  size_t off = 0;
  auto carve = [&](size_t bytes) -> char* {
    char* q = base + off;
    off += (bytes + 255) & ~(size_t)255;
    return q;
  };
  float* a_sp     = (float*)carve((size_t)N * 4);
  float* a_dp     = (float*)carve((size_t)N * 4);
  float* a_sc     = (float*)carve((size_t)N * 4);
  float* a_dc     = (float*)carve((size_t)N * 4);
  int*   qid      = (int*)carve((size_t)N * 4);
  int*   uniq     = (int*)carve((size_t)S * 4);
  int*   counters = (int*)carve(64);                    // [0]=U [1]=cntP [2]=cntC [3]=cntR
  float* vvec     = (float*)carve(5 * D * 4);
  float* num_p    = (float*)carve((size_t)S * D * 4);
  float* den_p    = (float*)carve((size_t)S * 4);
  float* num_c    = (float*)carve((size_t)S * D * 4);
  float* den_c    = (float*)carve((size_t)S * 4);
  float* sum_r    = (float*)carve((size_t)S * D * 4);
  int*   deg_r    = (int*)carve((size_t)S * 4);
  float* outU     = (float*)carve((size_t)S * D * 4);
  float* scal     = (float*)carve((size_t)S * 8 * 4);
  int2*  lsu      = (int2*)carve((size_t)E * 8);        // reused parent/child
  float* lw       = (float*)carve((size_t)E * 4);
  int2*  lsuR     = (int2*)carve((size_t)E * 8);
  (void)ws_size; (void)n_in; (void)out_size;

  // zero-init (d_ws is poisoned 0xAA before every timed launch)
  hipMemsetAsync(qid, 0xFF, (size_t)N * 4, stream);     // -1
  hipMemsetAsync(counters, 0, 64, stream);
  hipMemsetAsync(num_p, 0, (size_t)S * D * 4, stream);
  hipMemsetAsync(den_p, 0, (size_t)S * 4, stream);
  hipMemsetAsync(num_c, 0, (size_t)S * D * 4, stream);
  hipMemsetAsync(den_c, 0, (size_t)S * 4, stream);
  hipMemsetAsync(sum_r, 0, (size_t)S * D * 4, stream);
  hipMemsetAsync(deg_r, 0, (size_t)S * 4, stream);

  k_build_qid<<<(S + 255) / 256, 256, 0, stream>>>(s, qid, uniq, counters, S);
  k_calc_v<<<1, 128, 0, stream>>>(Wp, asp, adp, Wc, asc, adc, bp, bc, bl, vvec);
  k_a<<<(N + 3) / 4, 256, 0, stream>>>(emb, vvec, a_sp, a_dp, a_sc, a_dc, N);

  // edge filtering + raw-emb aggregation (W applied later, only on U rows)
  const int FB = (E + 1023) / 1024;
  k_sage_filter<<<FB, 1024, 0, stream>>>(eir, qid, lsuR, deg_r, counters + 3, E);
  k_sage_accum<<<1024, 256, 0, stream>>>(lsuR, emb, sum_r, counters + 3);

  k_gat_filter<<<FB, 1024, 0, stream>>>(eip, a_sp, a_dp, qid, lsu, lw, den_p, counters + 1, E);
  k_gat_accum<<<1024, 256, 0, stream>>>(lsu, lw, emb, num_p, counters + 1);

  k_gat_filter<<<FB, 1024, 0, stream>>>(eic, a_sc, a_dc, qid, lsu, lw, den_c, counters + 2, E);
  k_gat_accum<<<1024, 256, 0, stream>>>(lsu, lw, emb, num_c, counters + 2);

  k_scalars<<<(S + 255) / 256, 256, 0, stream>>>(uniq, counters, a_sp, a_dp, a_sc, a_dc,
                                                 den_p, den_c, deg_r, scal);
  k_final<<<(S + 15) / 16, 256, 0, stream>>>(num_p, num_c, sum_r, emb, uniq, counters,
                                             scal, Wp, Wc, Wl, Wr, outU);
  k_gather<<<(S * D + 255) / 256, 256, 0, stream>>>(s, qid, outU, vvec, out, S);
}

// Round 4
// 304.984 us; speedup vs baseline: 3.9532x; 1.5149x over previous
//
#include <hip/hip_runtime.h>

#define D 128

// ---------------- kernels ----------------

__global__ void k_build_qid(const int* __restrict__ s, int* __restrict__ qid,
                            int* __restrict__ uniq, int* __restrict__ counters, int S) {
  int i = blockIdx.x * blockDim.x + threadIdx.x;
  if (i >= S) return;
  int n = s[i];
  if (atomicCAS(&qid[n], -1, -2) == -1) {
    int u = atomicAdd(&counters[0], 1);
    uniq[u] = n;
    qid[n] = u;
  }
}

// v = [Wp@asp, Wp@adp, Wc@asc, Wc@adc, bp+bc+bl]
__global__ void k_calc_v(const float* __restrict__ Wp, const float* __restrict__ asp,
                         const float* __restrict__ adp, const float* __restrict__ Wc,
                         const float* __restrict__ asc, const float* __restrict__ adc,
                         const float* __restrict__ bp, const float* __restrict__ bc,
                         const float* __restrict__ bl, float* __restrict__ v) {
  int k = threadIdx.x;  // 0..127
  float s0 = 0.f, s1 = 0.f, s2 = 0.f, s3 = 0.f;
  for (int d = 0; d < D; ++d) {
    float wp = Wp[k * D + d], wc = Wc[k * D + d];
    s0 += wp * asp[d]; s1 += wp * adp[d];
    s2 += wc * asc[d]; s3 += wc * adc[d];
  }
  v[k] = s0; v[D + k] = s1; v[2 * D + k] = s2; v[3 * D + k] = s3;
  v[4 * D + k] = bp[k] + bc[k] + bl[k];
}

// per-node attention scalars: a_* = emb[n] . v_*   (one wave per node)
__global__ void k_a(const float* __restrict__ emb, const float* __restrict__ v,
                    float* __restrict__ a_sp, float* __restrict__ a_dp,
                    float* __restrict__ a_sc, float* __restrict__ a_dc, int N) {
  int gtid = blockIdx.x * blockDim.x + threadIdx.x;
  int node = gtid >> 6;
  int lane = threadIdx.x & 63;
  if (node >= N) return;
  float2 x2 = ((const float2*)(emb + (size_t)node * D))[lane];
  float2 v0 = ((const float2*)(v))[lane];
  float2 v1 = ((const float2*)(v + D))[lane];
  float2 v2 = ((const float2*)(v + 2 * D))[lane];
  float2 v3 = ((const float2*)(v + 3 * D))[lane];
  float s0 = x2.x * v0.x + x2.y * v0.y;
  float s1 = x2.x * v1.x + x2.y * v1.y;
  float s2 = x2.x * v2.x + x2.y * v2.y;
  float s3 = x2.x * v3.x + x2.y * v3.y;
  for (int o = 32; o > 0; o >>= 1) {
    s0 += __shfl_down(s0, o);
    s1 += __shfl_down(s1, o);
    s2 += __shfl_down(s2, o);
    s3 += __shfl_down(s3, o);
  }
  if (lane == 0) { a_sp[node] = s0; a_dp[node] = s1; a_sc[node] = s2; a_dc[node] = s3; }
}

// unified filter (blockIdx.y = relation): compact {src,u}, count deg[u].
__global__ void __launch_bounds__(1024) k_filter(
    const int* __restrict__ eiP, const int* __restrict__ eiC, const int* __restrict__ eiR,
    const int* __restrict__ qid,
    int2* __restrict__ lsuP, int2* __restrict__ lsuC, int2* __restrict__ lsuR,
    int* __restrict__ degP, int* __restrict__ degC, int* __restrict__ degR,
    int* __restrict__ counters, int E) {
  int rel = blockIdx.y;
  const int* ei = (rel == 0) ? eiP : (rel == 1) ? eiC : eiR;
  int2* lsu     = (rel == 0) ? lsuP : (rel == 1) ? lsuC : lsuR;
  int* deg      = (rel == 0) ? degP : (rel == 1) ? degC : degR;
  int* cnt      = counters + 1 + rel;

  int e = blockIdx.x * 1024 + threadIdx.x;
  bool active = false;
  int src = 0, u = 0;
  if (e < E) {
    int dst = ei[E + e];
    u = qid[dst];
    if (u >= 0) { src = ei[e]; active = true; }
  }
  unsigned long long mask = __ballot(active);
  int lane = threadIdx.x & 63;
  int wid = threadIdx.x >> 6;           // 0..15
  __shared__ int wbase[16];
  if (lane == 0) wbase[wid] = __popcll(mask);
  __syncthreads();
  if (threadIdx.x == 0) {
    int tot = 0, pref[16];
#pragma unroll
    for (int i = 0; i < 16; ++i) { pref[i] = tot; tot += wbase[i]; }
    int b = atomicAdd(cnt, tot);
#pragma unroll
    for (int i = 0; i < 16; ++i) wbase[i] = b + pref[i];
  }
  __syncthreads();
  if (active) {
    int pos = wbase[wid] + __popcll(mask & ((1ULL << lane) - 1));
    int2 su; su.x = src; su.y = u;
    lsu[pos] = su;
    atomicAdd(&deg[u], 1);
  }
}

// exclusive scan of deg -> rowoff (+ working cursor copy). blockIdx.x = relation.
// single block of 1024 threads, 16 elems/thread covers U <= 16384.
__global__ void __launch_bounds__(1024) k_scan(
    const int* __restrict__ degP, const int* __restrict__ degC, const int* __restrict__ degR,
    int* __restrict__ roffP, int* __restrict__ roffC, int* __restrict__ roffR,
    int* __restrict__ curP, int* __restrict__ curC, int* __restrict__ curR,
    const int* __restrict__ counters) {
  int rel = blockIdx.x;
  const int* deg = (rel == 0) ? degP : (rel == 1) ? degC : degR;
  int* roff      = (rel == 0) ? roffP : (rel == 1) ? roffC : roffR;
  int* cur       = (rel == 0) ? curP : (rel == 1) ? curC : curR;
  int U = counters[0];
  __shared__ int ssum[1024];
  int t = threadIdx.x;
  int base = t * 16;
  int vals[16];
  int s = 0;
#pragma unroll
  for (int i = 0; i < 16; ++i) {
    int idx = base + i;
    int v = (idx < U) ? deg[idx] : 0;
    vals[i] = s; s += v;
  }
  ssum[t] = s;
  __syncthreads();
  for (int off = 1; off < 1024; off <<= 1) {
    int v = (t >= off) ? ssum[t - off] : 0;
    __syncthreads();
    ssum[t] += v;
    __syncthreads();
  }
  int pre = (t == 0) ? 0 : ssum[t - 1];
#pragma unroll
  for (int i = 0; i < 16; ++i) {
    int idx = base + i;
    if (idx < U) { int o = pre + vals[i]; roff[idx] = o; cur[idx] = o; }
  }
}

// scatter compact edges into CSR segments. blockIdx.y = relation.
__global__ void k_scatter(
    const int2* __restrict__ lsuP, const int2* __restrict__ lsuC, const int2* __restrict__ lsuR,
    int* __restrict__ csrP, int* __restrict__ csrC, int* __restrict__ csrR,
    int* __restrict__ curP, int* __restrict__ curC, int* __restrict__ curR,
    const int* __restrict__ counters) {
  int rel = blockIdx.y;
  const int2* lsu = (rel == 0) ? lsuP : (rel == 1) ? lsuC : lsuR;
  int* csr        = (rel == 0) ? csrP : (rel == 1) ? csrC : csrR;
  int* cur        = (rel == 0) ? curP : (rel == 1) ? curC : curR;
  int n = counters[1 + rel];
  for (int i = blockIdx.x * blockDim.x + threadIdx.x; i < n;
       i += gridDim.x * blockDim.x) {
    int2 su = lsu[i];
    int pos = atomicAdd(&cur[su.y], 1);
    csr[pos] = su.x;
  }
}

// one wave per (u, relation): register accumulation, single row store. No atomics.
__global__ void __launch_bounds__(256) k_accum(
    const int* __restrict__ csrP, const int* __restrict__ csrC, const int* __restrict__ csrR,
    const int* __restrict__ roffP, const int* __restrict__ roffC, const int* __restrict__ roffR,
    const int* __restrict__ degP, const int* __restrict__ degC, const int* __restrict__ degR,
    const float* __restrict__ a_sp, const float* __restrict__ a_dp,
    const float* __restrict__ a_sc, const float* __restrict__ a_dc,
    const float* __restrict__ emb, const int* __restrict__ uniq,
    const int* __restrict__ counters,
    float* __restrict__ num_p, float* __restrict__ num_c, float* __restrict__ sum_r,
    float* __restrict__ den_p, float* __restrict__ den_c) {
  int U = counters[0];
  int u = blockIdx.x * 4 + (threadIdx.x >> 6);
  if (u >= U) return;
  int lane = threadIdx.x & 63;
  int rel = blockIdx.y;
  const int* csr  = (rel == 0) ? csrP : (rel == 1) ? csrC : csrR;
  const int* roff = (rel == 0) ? roffP : (rel == 1) ? roffC : roffR;
  const int* deg  = (rel == 0) ? degP : (rel == 1) ? degC : degR;
  float* num      = (rel == 0) ? num_p : (rel == 1) ? num_c : sum_r;

  int start = roff[u];
  int m = deg[u];
  float2 acc; acc.x = 0.f; acc.y = 0.f;

  if (rel == 2) {
    for (int c = 0; c < m; c += 64) {
      int mm = min(64, m - c);
      int srcl = (lane < mm) ? csr[start + c + lane] : 0;
      for (int i = 0; i < mm; ++i) {
        int si = __shfl(srcl, i);
        float2 x2 = ((const float2*)(emb + (size_t)si * D))[lane];
        acc.x += x2.x; acc.y += x2.y;
      }
    }
  } else {
    const float* a_s = (rel == 0) ? a_sp : a_sc;
    const float* a_d = (rel == 0) ? a_dp : a_dc;
    int n = uniq[u];
    float adn = a_d[n];
    float denl = 0.f;
    for (int c = 0; c < m; c += 64) {
      int mm = min(64, m - c);
      int srcl = (lane < mm) ? csr[start + c + lane] : 0;
      float wl = 0.f;
      if (lane < mm) {
        float t = a_s[srcl] + adn;
        t = t >= 0.f ? t : 0.2f * t;
        wl = __expf(t);
      }
      denl += wl;
      for (int i = 0; i < mm; ++i) {
        int si = __shfl(srcl, i);
        float wi = __shfl(wl, i);
        float2 x2 = ((const float2*)(emb + (size_t)si * D))[lane];
        acc.x += wi * x2.x; acc.y += wi * x2.y;
      }
    }
    for (int o = 32; o > 0; o >>= 1) denl += __shfl_down(denl, o);
    if (lane == 0) { ((rel == 0) ? den_p : den_c)[u] = denl; }
  }
  ((float2*)(num + (size_t)u * D))[lane] = acc;
}

// per-u scalars: [wP, 1/(denP+wP), wC, 1/(denC+wC), 1/max(deg,1)]
__global__ void k_scalars(const int* __restrict__ uniq, const int* __restrict__ counters,
                          const float* __restrict__ a_sp, const float* __restrict__ a_dp,
                          const float* __restrict__ a_sc, const float* __restrict__ a_dc,
                          const float* __restrict__ den_p, const float* __restrict__ den_c,
                          const int* __restrict__ deg_r, float* __restrict__ scal) {
  int u = blockIdx.x * blockDim.x + threadIdx.x;
  if (u >= counters[0]) return;
  int n = uniq[u];
  float tP = a_sp[n] + a_dp[n]; tP = tP >= 0.f ? tP : 0.2f * tP;
  float wP = __expf(tP);
  float tC = a_sc[n] + a_dc[n]; tC = tC >= 0.f ? tC : 0.2f * tC;
  float wC = __expf(tC);
  float dg = (float)deg_r[u]; if (dg < 1.f) dg = 1.f;
  float* sc = scal + (size_t)u * 8;
  sc[0] = wP; sc[1] = 1.f / (den_p[u] + wP);
  sc[2] = wC; sc[3] = 1.f / (den_c[u] + wC);
  sc[4] = 1.f / dg;
}

// fused final: outU[u] = aggP@Wp + aggC@Wc + aggR@Wl + emb[n]@Wr
__global__ void __launch_bounds__(256) k_final(
    const float* __restrict__ num_p, const float* __restrict__ num_c,
    const float* __restrict__ sum_r, const float* __restrict__ emb,
    const int* __restrict__ uniq, const int* __restrict__ counters,
    const float* __restrict__ scal,
    const float* __restrict__ Wp, const float* __restrict__ Wc,
    const float* __restrict__ Wl, const float* __restrict__ Wr,
    float* __restrict__ outU) {
  __shared__ float zs[4][16][D];   // 32 KB: z-rows then partial sums
  int U = counters[0];
  int u0 = blockIdx.x * 16;
  if (u0 >= U) return;
  int tid = threadIdx.x;

  for (int t = tid; t < 512; t += 256) {
    int j = t >> 5;
    int c4 = (t & 31) * 4;
    int u = u0 + j;
    int uu = (u < U) ? u : u0;
    int n = uniq[uu];
    const float* sc = scal + (size_t)uu * 8;
    float wP = sc[0], rP = sc[1], wC = sc[2], rC = sc[3], rdeg = sc[4];
    float4 e4  = *(const float4*)(emb   + (size_t)n  * D + c4);
    float4 np4 = *(const float4*)(num_p + (size_t)uu * D + c4);
    float4 nc4 = *(const float4*)(num_c + (size_t)uu * D + c4);
    float4 sr4 = *(const float4*)(sum_r + (size_t)uu * D + c4);
    float4 z0, z1, z2;
    z0.x = (np4.x + wP * e4.x) * rP; z0.y = (np4.y + wP * e4.y) * rP;
    z0.z = (np4.z + wP * e4.z) * rP; z0.w = (np4.w + wP * e4.w) * rP;
    z1.x = (nc4.x + wC * e4.x) * rC; z1.y = (nc4.y + wC * e4.y) * rC;
    z1.z = (nc4.z + wC * e4.z) * rC; z1.w = (nc4.w + wC * e4.w) * rC;
    z2.x = sr4.x * rdeg; z2.y = sr4.y * rdeg; z2.z = sr4.z * rdeg; z2.w = sr4.w * rdeg;
    *(float4*)&zs[0][j][c4] = z0;
    *(float4*)&zs[1][j][c4] = z1;
    *(float4*)&zs[2][j][c4] = z2;
    *(float4*)&zs[3][j][c4] = e4;
  }
  __syncthreads();

  int o = tid >> 6;        // wave id == operand
  int lane = tid & 63;
  int c0 = lane, c1 = lane + 64;
  const float* W = (o == 0) ? Wp : (o == 1) ? Wc : (o == 2) ? Wl : Wr;

  float acc0[16], acc1[16];
#pragma unroll
  for (int j = 0; j < 16; ++j) { acc0[j] = 0.f; acc1[j] = 0.f; }

  float wcur[8], wnext[8];
#pragma unroll
  for (int kk = 0; kk < 4; ++kk) {
    wcur[kk]     = W[kk * D + c0];
    wcur[4 + kk] = W[kk * D + c1];
  }
  for (int c = 0; c < 32; ++c) {
    int kb = c * 4;
    if (c < 31) {
#pragma unroll
      for (int kk = 0; kk < 4; ++kk) {
        wnext[kk]     = W[(kb + 4 + kk) * D + c0];
        wnext[4 + kk] = W[(kb + 4 + kk) * D + c1];
      }
    }
#pragma unroll
    for (int j = 0; j < 16; ++j) {
      float4 v = *(const float4*)&zs[o][j][kb];
      acc0[j] += v.x * wcur[0] + v.y * wcur[1] + v.z * wcur[2] + v.w * wcur[3];
      acc1[j] += v.x * wcur[4] + v.y * wcur[5] + v.z * wcur[6] + v.w * wcur[7];
    }
#pragma unroll
    for (int kk = 0; kk < 8; ++kk) wcur[kk] = wnext[kk];
  }
  __syncthreads();

#pragma unroll
  for (int j = 0; j < 16; ++j) {
    zs[o][j][c0] = acc0[j];
    zs[o][j][c1] = acc1[j];
  }
  __syncthreads();

  int col = tid & 127;
  int j0 = (tid >> 7) * 8;
#pragma unroll
  for (int jj = 0; jj < 8; ++jj) {
    int j = j0 + jj;
    int u = u0 + j;
    if (u < U) {
      float s = zs[0][j][col] + zs[1][j][col] + zs[2][j][col] + zs[3][j][col];
      outU[(size_t)u * D + col] = s;
    }
  }
}

__global__ void k_gather(const int* __restrict__ s, const int* __restrict__ qid,
                         const float* __restrict__ outU, const float* __restrict__ v,
                         float* __restrict__ out, int S) {
  int idx = blockIdx.x * blockDim.x + threadIdx.x;
  if (idx >= S * D) return;
  int i = idx >> 7;
  int d = idx & (D - 1);
  int u = qid[s[i]];
  out[idx] = (outU[(size_t)u * D + d] + v[4 * D + d]) * (1.f / 3.f);
}

// ---------------- launch ----------------

extern "C" void kernel_launch(void* const* d_in, const int* in_sizes, int n_in,
                              void* d_out, int out_size, void* d_ws, size_t ws_size,
                              hipStream_t stream) {
  const int*   s   = (const int*)d_in[0];
  const int*   eip = (const int*)d_in[3];
  const int*   eic = (const int*)d_in[4];
  const int*   eir = (const int*)d_in[5];
  const float* emb = (const float*)d_in[6];
  const float* Wp  = (const float*)d_in[7];
  const float* asp = (const float*)d_in[8];
  const float* adp = (const float*)d_in[9];
  const float* bp  = (const float*)d_in[10];
  const float* Wc  = (const float*)d_in[11];
  const float* asc = (const float*)d_in[12];
  const float* adc = (const float*)d_in[13];
  const float* bc  = (const float*)d_in[14];
  const float* Wl  = (const float*)d_in[15];
  const float* bl  = (const float*)d_in[16];
  const float* Wr  = (const float*)d_in[17];
  float* out = (float*)d_out;

  const int S = in_sizes[0];
  const int E = in_sizes[3] / 2;
  const int N = in_sizes[6] / D;

  char* base = (char*)d_ws;
  size_t off = 0;
  auto carve = [&](size_t bytes) -> char* {
    char* q = base + off;
    off += (bytes + 255) & ~(size_t)255;
    return q;
  };
  float* a_sp     = (float*)carve((size_t)N * 4);
  float* a_dp     = (float*)carve((size_t)N * 4);
  float* a_sc     = (float*)carve((size_t)N * 4);
  float* a_dc     = (float*)carve((size_t)N * 4);
  int*   qid      = (int*)carve((size_t)N * 4);
  int*   uniq     = (int*)carve((size_t)S * 4);
  int*   counters = (int*)carve(64);                    // [0]=U [1]=cntP [2]=cntC [3]=cntR
  float* vvec     = (float*)carve(5 * D * 4);
  float* num_p    = (float*)carve((size_t)S * D * 4);
  float* den_p    = (float*)carve((size_t)S * 4);
  float* num_c    = (float*)carve((size_t)S * D * 4);
  float* den_c    = (float*)carve((size_t)S * 4);
  float* sum_r    = (float*)carve((size_t)S * D * 4);
  float* outU     = (float*)carve((size_t)S * D * 4);
  float* scal     = (float*)carve((size_t)S * 8 * 4);
  int*   degP     = (int*)carve((size_t)S * 4);
  int*   degC     = (int*)carve((size_t)S * 4);
  int*   degR     = (int*)carve((size_t)S * 4);
  int*   roffP    = (int*)carve((size_t)S * 4);
  int*   roffC    = (int*)carve((size_t)S * 4);
  int*   roffR    = (int*)carve((size_t)S * 4);
  int*   curP     = (int*)carve((size_t)S * 4);
  int*   curC     = (int*)carve((size_t)S * 4);
  int*   curR     = (int*)carve((size_t)S * 4);
  int2*  lsuP     = (int2*)carve((size_t)E * 8);
  int2*  lsuC     = (int2*)carve((size_t)E * 8);
  int2*  lsuR     = (int2*)carve((size_t)E * 8);
  int*   csrP     = (int*)carve((size_t)E * 4);
  int*   csrC     = (int*)carve((size_t)E * 4);
  int*   csrR     = (int*)carve((size_t)E * 4);
  (void)ws_size; (void)n_in; (void)out_size;

  hipMemsetAsync(qid, 0xFF, (size_t)N * 4, stream);     // -1
  hipMemsetAsync(counters, 0, 64, stream);
  hipMemsetAsync(degP, 0, (size_t)S * 4 * 3, stream);   // degP/degC/degR contiguous

  k_build_qid<<<(S + 255) / 256, 256, 0, stream>>>(s, qid, uniq, counters, S);
  k_calc_v<<<1, 128, 0, stream>>>(Wp, asp, adp, Wc, asc, adc, bp, bc, bl, vvec);
  k_a<<<(N + 3) / 4, 256, 0, stream>>>(emb, vvec, a_sp, a_dp, a_sc, a_dc, N);

  const int FB = (E + 1023) / 1024;
  k_filter<<<dim3(FB, 3), 1024, 0, stream>>>(eip, eic, eir, qid, lsuP, lsuC, lsuR,
                                             degP, degC, degR, counters, E);
  k_scan<<<3, 1024, 0, stream>>>(degP, degC, degR, roffP, roffC, roffR,
                                 curP, curC, curR, counters);
  k_scatter<<<dim3(128, 3), 256, 0, stream>>>(lsuP, lsuC, lsuR, csrP, csrC, csrR,
                                              curP, curC, curR, counters);
  k_accum<<<dim3((S + 3) / 4, 3), 256, 0, stream>>>(
      csrP, csrC, csrR, roffP, roffC, roffR, degP, degC, degR,
      a_sp, a_dp, a_sc, a_dc, emb, uniq, counters,
      num_p, num_c, sum_r, den_p, den_c);

  k_scalars<<<(S + 255) / 256, 256, 0, stream>>>(uniq, counters, a_sp, a_dp, a_sc, a_dc,
                                                 den_p, den_c, degR, scal);
  k_final<<<(S + 15) / 16, 256, 0, stream>>>(num_p, num_c, sum_r, emb, uniq, counters,
                                             scal, Wp, Wc, Wl, Wr, outU);
  k_gather<<<(S * D + 255) / 256, 256, 0, stream>>>(s, qid, outU, vvec, out, S);
}

// Round 5
// 298.824 us; speedup vs baseline: 4.0347x; 1.0206x over previous
//
#include <hip/hip_runtime.h>

#define D 128

// ---------------- kernels ----------------

// one kernel replaces 3 memsets: qid=-1 (N), counters=0 (16), deg[3S]=0
__global__ void k_init(int* __restrict__ qid, int* __restrict__ counters,
                       int* __restrict__ deg3, int N, int S3) {
  int i = blockIdx.x * blockDim.x + threadIdx.x;
  int stride = gridDim.x * blockDim.x;
  for (int k = i; k < N; k += stride) qid[k] = -1;
  for (int k = i; k < S3; k += stride) deg3[k] = 0;
  if (i < 16) counters[i] = 0;
}

__global__ void k_build_qid(const int* __restrict__ s, int* __restrict__ qid,
                            int* __restrict__ uniq, int* __restrict__ counters, int S) {
  int i = blockIdx.x * blockDim.x + threadIdx.x;
  if (i >= S) return;
  int n = s[i];
  if (atomicCAS(&qid[n], -1, -2) == -1) {
    int u = atomicAdd(&counters[0], 1);
    uniq[u] = n;
    qid[n] = u;
  }
}

// v = [Wp@asp, Wp@adp, Wc@asc, Wc@adc, bp+bc+bl]
__global__ void k_calc_v(const float* __restrict__ Wp, const float* __restrict__ asp,
                         const float* __restrict__ adp, const float* __restrict__ Wc,
                         const float* __restrict__ asc, const float* __restrict__ adc,
                         const float* __restrict__ bp, const float* __restrict__ bc,
                         const float* __restrict__ bl, float* __restrict__ v) {
  int k = threadIdx.x;  // 0..127
  float s0 = 0.f, s1 = 0.f, s2 = 0.f, s3 = 0.f;
  for (int d = 0; d < D; ++d) {
    float wp = Wp[k * D + d], wc = Wc[k * D + d];
    s0 += wp * asp[d]; s1 += wp * adp[d];
    s2 += wc * asc[d]; s3 += wc * adc[d];
  }
  v[k] = s0; v[D + k] = s1; v[2 * D + k] = s2; v[3 * D + k] = s3;
  v[4 * D + k] = bp[k] + bc[k] + bl[k];
}

// per-node attention scalars: a_* = emb[n] . v_*   (one wave per node)
__global__ void k_a(const float* __restrict__ emb, const float* __restrict__ v,
                    float* __restrict__ a_sp, float* __restrict__ a_dp,
                    float* __restrict__ a_sc, float* __restrict__ a_dc, int N) {
  int gtid = blockIdx.x * blockDim.x + threadIdx.x;
  int node = gtid >> 6;
  int lane = threadIdx.x & 63;
  if (node >= N) return;
  float2 x2 = ((const float2*)(emb + (size_t)node * D))[lane];
  float2 v0 = ((const float2*)(v))[lane];
  float2 v1 = ((const float2*)(v + D))[lane];
  float2 v2 = ((const float2*)(v + 2 * D))[lane];
  float2 v3 = ((const float2*)(v + 3 * D))[lane];
  float s0 = x2.x * v0.x + x2.y * v0.y;
  float s1 = x2.x * v1.x + x2.y * v1.y;
  float s2 = x2.x * v2.x + x2.y * v2.y;
  float s3 = x2.x * v3.x + x2.y * v3.y;
  for (int o = 32; o > 0; o >>= 1) {
    s0 += __shfl_down(s0, o);
    s1 += __shfl_down(s1, o);
    s2 += __shfl_down(s2, o);
    s3 += __shfl_down(s3, o);
  }
  if (lane == 0) { a_sp[node] = s0; a_dp[node] = s1; a_sc[node] = s2; a_dc[node] = s3; }
}

// unified filter (blockIdx.y = relation): compact {src,u}, count deg[u].
__global__ void __launch_bounds__(1024) k_filter(
    const int* __restrict__ eiP, const int* __restrict__ eiC, const int* __restrict__ eiR,
    const int* __restrict__ qid,
    int2* __restrict__ lsuP, int2* __restrict__ lsuC, int2* __restrict__ lsuR,
    int* __restrict__ degP, int* __restrict__ degC, int* __restrict__ degR,
    int* __restrict__ counters, int E) {
  int rel = blockIdx.y;
  const int* ei = (rel == 0) ? eiP : (rel == 1) ? eiC : eiR;
  int2* lsu     = (rel == 0) ? lsuP : (rel == 1) ? lsuC : lsuR;
  int* deg      = (rel == 0) ? degP : (rel == 1) ? degC : degR;
  int* cnt      = counters + 1 + rel;

  int e = blockIdx.x * 1024 + threadIdx.x;
  bool active = false;
  int src = 0, u = 0;
  if (e < E) {
    int dst = ei[E + e];
    u = qid[dst];
    if (u >= 0) { src = ei[e]; active = true; }
  }
  unsigned long long mask = __ballot(active);
  int lane = threadIdx.x & 63;
  int wid = threadIdx.x >> 6;           // 0..15
  __shared__ int wbase[16];
  if (lane == 0) wbase[wid] = __popcll(mask);
  __syncthreads();
  if (threadIdx.x == 0) {
    int tot = 0, pref[16];
#pragma unroll
    for (int i = 0; i < 16; ++i) { pref[i] = tot; tot += wbase[i]; }
    int b = atomicAdd(cnt, tot);
#pragma unroll
    for (int i = 0; i < 16; ++i) wbase[i] = b + pref[i];
  }
  __syncthreads();
  if (active) {
    int pos = wbase[wid] + __popcll(mask & ((1ULL << lane) - 1));
    int2 su; su.x = src; su.y = u;
    lsu[pos] = su;
    atomicAdd(&deg[u], 1);
  }
}

// exclusive scan of deg -> rowoff (+ working cursor copy). blockIdx.x = relation.
__global__ void __launch_bounds__(1024) k_scan(
    const int* __restrict__ degP, const int* __restrict__ degC, const int* __restrict__ degR,
    int* __restrict__ roffP, int* __restrict__ roffC, int* __restrict__ roffR,
    int* __restrict__ curP, int* __restrict__ curC, int* __restrict__ curR,
    const int* __restrict__ counters) {
  int rel = blockIdx.x;
  const int* deg = (rel == 0) ? degP : (rel == 1) ? degC : degR;
  int* roff      = (rel == 0) ? roffP : (rel == 1) ? roffC : roffR;
  int* cur       = (rel == 0) ? curP : (rel == 1) ? curC : curR;
  int U = counters[0];
  __shared__ int ssum[1024];
  int t = threadIdx.x;
  int base = t * 16;
  int vals[16];
  int s = 0;
#pragma unroll
  for (int i = 0; i < 16; ++i) {
    int idx = base + i;
    int v = (idx < U) ? deg[idx] : 0;
    vals[i] = s; s += v;
  }
  ssum[t] = s;
  __syncthreads();
  for (int off = 1; off < 1024; off <<= 1) {
    int v = (t >= off) ? ssum[t - off] : 0;
    __syncthreads();
    ssum[t] += v;
    __syncthreads();
  }
  int pre = (t == 0) ? 0 : ssum[t - 1];
#pragma unroll
  for (int i = 0; i < 16; ++i) {
    int idx = base + i;
    if (idx < U) { int o = pre + vals[i]; roff[idx] = o; cur[idx] = o; }
  }
}

// scatter compact edges into CSR segments. blockIdx.y = relation.
__global__ void k_scatter(
    const int2* __restrict__ lsuP, const int2* __restrict__ lsuC, const int2* __restrict__ lsuR,
    int* __restrict__ csrP, int* __restrict__ csrC, int* __restrict__ csrR,
    int* __restrict__ curP, int* __restrict__ curC, int* __restrict__ curR,
    const int* __restrict__ counters) {
  int rel = blockIdx.y;
  const int2* lsu = (rel == 0) ? lsuP : (rel == 1) ? lsuC : lsuR;
  int* csr        = (rel == 0) ? csrP : (rel == 1) ? csrC : csrR;
  int* cur        = (rel == 0) ? curP : (rel == 1) ? curC : curR;
  int n = counters[1 + rel];
  for (int i = blockIdx.x * blockDim.x + threadIdx.x; i < n;
       i += gridDim.x * blockDim.x) {
    int2 su = lsu[i];
    int pos = atomicAdd(&cur[su.y], 1);
    csr[pos] = su.x;
  }
}

// one wave per (u, relation): register accumulation, single row store. No atomics.
__global__ void __launch_bounds__(256) k_accum(
    const int* __restrict__ csrP, const int* __restrict__ csrC, const int* __restrict__ csrR,
    const int* __restrict__ roffP, const int* __restrict__ roffC, const int* __restrict__ roffR,
    const int* __restrict__ degP, const int* __restrict__ degC, const int* __restrict__ degR,
    const float* __restrict__ a_sp, const float* __restrict__ a_dp,
    const float* __restrict__ a_sc, const float* __restrict__ a_dc,
    const float* __restrict__ emb, const int* __restrict__ uniq,
    const int* __restrict__ counters,
    float* __restrict__ num_p, float* __restrict__ num_c, float* __restrict__ sum_r,
    float* __restrict__ den_p, float* __restrict__ den_c) {
  int U = counters[0];
  int u = blockIdx.x * 4 + (threadIdx.x >> 6);
  if (u >= U) return;
  int lane = threadIdx.x & 63;
  int rel = blockIdx.y;
  const int* csr  = (rel == 0) ? csrP : (rel == 1) ? csrC : csrR;
  const int* roff = (rel == 0) ? roffP : (rel == 1) ? roffC : roffR;
  const int* deg  = (rel == 0) ? degP : (rel == 1) ? degC : degR;
  float* num      = (rel == 0) ? num_p : (rel == 1) ? num_c : sum_r;

  int start = roff[u];
  int m = deg[u];
  float2 acc; acc.x = 0.f; acc.y = 0.f;

  if (rel == 2) {
    for (int c = 0; c < m; c += 64) {
      int mm = min(64, m - c);
      int srcl = (lane < mm) ? csr[start + c + lane] : 0;
      for (int i = 0; i < mm; ++i) {
        int si = __shfl(srcl, i);
        float2 x2 = ((const float2*)(emb + (size_t)si * D))[lane];
        acc.x += x2.x; acc.y += x2.y;
      }
    }
  } else {
    const float* a_s = (rel == 0) ? a_sp : a_sc;
    const float* a_d = (rel == 0) ? a_dp : a_dc;
    int n = uniq[u];
    float adn = a_d[n];
    float denl = 0.f;
    for (int c = 0; c < m; c += 64) {
      int mm = min(64, m - c);
      int srcl = (lane < mm) ? csr[start + c + lane] : 0;
      float wl = 0.f;
      if (lane < mm) {
        float t = a_s[srcl] + adn;
        t = t >= 0.f ? t : 0.2f * t;
        wl = __expf(t);
      }
      denl += wl;
      for (int i = 0; i < mm; ++i) {
        int si = __shfl(srcl, i);
        float wi = __shfl(wl, i);
        float2 x2 = ((const float2*)(emb + (size_t)si * D))[lane];
        acc.x += wi * x2.x; acc.y += wi * x2.y;
      }
    }
    for (int o = 32; o > 0; o >>= 1) denl += __shfl_down(denl, o);
    if (lane == 0) { ((rel == 0) ? den_p : den_c)[u] = denl; }
  }
  ((float2*)(num + (size_t)u * D))[lane] = acc;
}

// fused final: outU[u] = (aggP@Wp + aggC@Wc + aggR@Wl + emb[n]@Wr + bias) / 3
// 8 u-rows per block (16 KB LDS, high occupancy); wave o owns matrix o.
__global__ void __launch_bounds__(256) k_final(
    const float* __restrict__ num_p, const float* __restrict__ num_c,
    const float* __restrict__ sum_r, const float* __restrict__ emb,
    const int* __restrict__ uniq, const int* __restrict__ counters,
    const float* __restrict__ a_sp, const float* __restrict__ a_dp,
    const float* __restrict__ a_sc, const float* __restrict__ a_dc,
    const float* __restrict__ den_p, const float* __restrict__ den_c,
    const int* __restrict__ deg_r, const float* __restrict__ vvec,
    const float* __restrict__ Wp, const float* __restrict__ Wc,
    const float* __restrict__ Wl, const float* __restrict__ Wr,
    float* __restrict__ outU) {
  __shared__ float zs[4][8][D];   // 16 KB: z-rows then partial sums
  int U = counters[0];
  int u0 = blockIdx.x * 8;
  if (u0 >= U) return;
  int tid = threadIdx.x;

  // staging (scalars fused): thread t -> row j = t>>5, 16B chunk c4 = (t&31)*4
  {
    int j = tid >> 5;
    int c4 = (tid & 31) * 4;
    int u = u0 + j;
    int uu = (u < U) ? u : u0;
    int n = uniq[uu];
    float tP = a_sp[n] + a_dp[n]; tP = tP >= 0.f ? tP : 0.2f * tP;
    float wP = __expf(tP);
    float rP = 1.f / (den_p[uu] + wP);
    float tC = a_sc[n] + a_dc[n]; tC = tC >= 0.f ? tC : 0.2f * tC;
    float wC = __expf(tC);
    float rC = 1.f / (den_c[uu] + wC);
    float dg = (float)deg_r[uu]; if (dg < 1.f) dg = 1.f;
    float rdeg = 1.f / dg;
    float4 e4  = *(const float4*)(emb   + (size_t)n  * D + c4);
    float4 np4 = *(const float4*)(num_p + (size_t)uu * D + c4);
    float4 nc4 = *(const float4*)(num_c + (size_t)uu * D + c4);
    float4 sr4 = *(const float4*)(sum_r + (size_t)uu * D + c4);
    float4 z0, z1, z2;
    z0.x = (np4.x + wP * e4.x) * rP; z0.y = (np4.y + wP * e4.y) * rP;
    z0.z = (np4.z + wP * e4.z) * rP; z0.w = (np4.w + wP * e4.w) * rP;
    z1.x = (nc4.x + wC * e4.x) * rC; z1.y = (nc4.y + wC * e4.y) * rC;
    z1.z = (nc4.z + wC * e4.z) * rC; z1.w = (nc4.w + wC * e4.w) * rC;
    z2.x = sr4.x * rdeg; z2.y = sr4.y * rdeg; z2.z = sr4.z * rdeg; z2.w = sr4.w * rdeg;
    *(float4*)&zs[0][j][c4] = z0;
    *(float4*)&zs[1][j][c4] = z1;
    *(float4*)&zs[2][j][c4] = z2;
    *(float4*)&zs[3][j][c4] = e4;
  }
  __syncthreads();

  int o = tid >> 6;        // wave id == operand
  int lane = tid & 63;
  int c0 = lane, c1 = lane + 64;
  const float* W = (o == 0) ? Wp : (o == 1) ? Wc : (o == 2) ? Wl : Wr;

  float acc0[8], acc1[8];
#pragma unroll
  for (int j = 0; j < 8; ++j) { acc0[j] = 0.f; acc1[j] = 0.f; }

  float wcur[8], wnext[8];
#pragma unroll
  for (int kk = 0; kk < 4; ++kk) {
    wcur[kk]     = W[kk * D + c0];
    wcur[4 + kk] = W[kk * D + c1];
  }
  for (int c = 0; c < 32; ++c) {
    int kb = c * 4;
    if (c < 31) {
#pragma unroll
      for (int kk = 0; kk < 4; ++kk) {
        wnext[kk]     = W[(kb + 4 + kk) * D + c0];
        wnext[4 + kk] = W[(kb + 4 + kk) * D + c1];
      }
    }
#pragma unroll
    for (int j = 0; j < 8; ++j) {
      float4 v = *(const float4*)&zs[o][j][kb];
      acc0[j] += v.x * wcur[0] + v.y * wcur[1] + v.z * wcur[2] + v.w * wcur[3];
      acc1[j] += v.x * wcur[4] + v.y * wcur[5] + v.z * wcur[6] + v.w * wcur[7];
    }
#pragma unroll
    for (int kk = 0; kk < 8; ++kk) wcur[kk] = wnext[kk];
  }
  __syncthreads();

#pragma unroll
  for (int j = 0; j < 8; ++j) {
    zs[o][j][c0] = acc0[j];
    zs[o][j][c1] = acc1[j];
  }
  __syncthreads();

  int col = tid & 127;
  int j0 = (tid >> 7) * 4;
  float b = (vvec[4 * D + col]) * (1.f / 3.f);
#pragma unroll
  for (int jj = 0; jj < 4; ++jj) {
    int j = j0 + jj;
    int u = u0 + j;
    if (u < U) {
      float s = zs[0][j][col] + zs[1][j][col] + zs[2][j][col] + zs[3][j][col];
      outU[(size_t)u * D + col] = s * (1.f / 3.f) + b;
    }
  }
}

// pure gather (bias and /3 already folded into outU)
__global__ void k_gather(const int* __restrict__ s, const int* __restrict__ qid,
                         const float* __restrict__ outU, float* __restrict__ out, int S) {
  int idx = blockIdx.x * blockDim.x + threadIdx.x;
  if (idx >= S * D) return;
  int i = idx >> 7;
  int d = idx & (D - 1);
  int u = qid[s[i]];
  out[idx] = outU[(size_t)u * D + d];
}

// ---------------- launch ----------------

extern "C" void kernel_launch(void* const* d_in, const int* in_sizes, int n_in,
                              void* d_out, int out_size, void* d_ws, size_t ws_size,
                              hipStream_t stream) {
  const int*   s   = (const int*)d_in[0];
  const int*   eip = (const int*)d_in[3];
  const int*   eic = (const int*)d_in[4];
  const int*   eir = (const int*)d_in[5];
  const float* emb = (const float*)d_in[6];
  const float* Wp  = (const float*)d_in[7];
  const float* asp = (const float*)d_in[8];
  const float* adp = (const float*)d_in[9];
  const float* bp  = (const float*)d_in[10];
  const float* Wc  = (const float*)d_in[11];
  const float* asc = (const float*)d_in[12];
  const float* adc = (const float*)d_in[13];
  const float* bc  = (const float*)d_in[14];
  const float* Wl  = (const float*)d_in[15];
  const float* bl  = (const float*)d_in[16];
  const float* Wr  = (const float*)d_in[17];
  float* out = (float*)d_out;

  const int S = in_sizes[0];
  const int E = in_sizes[3] / 2;
  const int N = in_sizes[6] / D;

  char* base = (char*)d_ws;
  size_t off = 0;
  auto carve = [&](size_t bytes) -> char* {
    char* q = base + off;
    off += (bytes + 255) & ~(size_t)255;
    return q;
  };
  float* a_sp     = (float*)carve((size_t)N * 4);
  float* a_dp     = (float*)carve((size_t)N * 4);
  float* a_sc     = (float*)carve((size_t)N * 4);
  float* a_dc     = (float*)carve((size_t)N * 4);
  int*   qid      = (int*)carve((size_t)N * 4);
  int*   uniq     = (int*)carve((size_t)S * 4);
  int*   counters = (int*)carve(64);                    // [0]=U [1]=cntP [2]=cntC [3]=cntR
  float* vvec     = (float*)carve(5 * D * 4);
  float* num_p    = (float*)carve((size_t)S * D * 4);
  float* den_p    = (float*)carve((size_t)S * 4);
  float* num_c    = (float*)carve((size_t)S * D * 4);
  float* den_c    = (float*)carve((size_t)S * 4);
  float* sum_r    = (float*)carve((size_t)S * D * 4);
  float* outU     = (float*)carve((size_t)S * D * 4);
  int*   degP     = (int*)carve((size_t)S * 4);         // degP/C/R contiguous (S*4 % 256 == 0)
  int*   degC     = (int*)carve((size_t)S * 4);
  int*   degR     = (int*)carve((size_t)S * 4);
  int*   roffP    = (int*)carve((size_t)S * 4);
  int*   roffC    = (int*)carve((size_t)S * 4);
  int*   roffR    = (int*)carve((size_t)S * 4);
  int*   curP     = (int*)carve((size_t)S * 4);
  int*   curC     = (int*)carve((size_t)S * 4);
  int*   curR     = (int*)carve((size_t)S * 4);
  int2*  lsuP     = (int2*)carve((size_t)E * 8);
  int2*  lsuC     = (int2*)carve((size_t)E * 8);
  int2*  lsuR     = (int2*)carve((size_t)E * 8);
  int*   csrP     = (int*)carve((size_t)E * 4);
  int*   csrC     = (int*)carve((size_t)E * 4);
  int*   csrR     = (int*)carve((size_t)E * 4);
  (void)ws_size; (void)n_in; (void)out_size;

  k_init<<<208, 512, 0, stream>>>(qid, counters, degP, N, 3 * S);

  k_build_qid<<<(S + 255) / 256, 256, 0, stream>>>(s, qid, uniq, counters, S);
  k_calc_v<<<1, 128, 0, stream>>>(Wp, asp, adp, Wc, asc, adc, bp, bc, bl, vvec);
  k_a<<<(N + 3) / 4, 256, 0, stream>>>(emb, vvec, a_sp, a_dp, a_sc, a_dc, N);

  const int FB = (E + 1023) / 1024;
  k_filter<<<dim3(FB, 3), 1024, 0, stream>>>(eip, eic, eir, qid, lsuP, lsuC, lsuR,
                                             degP, degC, degR, counters, E);
  k_scan<<<3, 1024, 0, stream>>>(degP, degC, degR, roffP, roffC, roffR,
                                 curP, curC, curR, counters);
  k_scatter<<<dim3(128, 3), 256, 0, stream>>>(lsuP, lsuC, lsuR, csrP, csrC, csrR,
                                              curP, curC, curR, counters);
  k_accum<<<dim3((S + 3) / 4, 3), 256, 0, stream>>>(
      csrP, csrC, csrR, roffP, roffC, roffR, degP, degC, degR,
      a_sp, a_dp, a_sc, a_dc, emb, uniq, counters,
      num_p, num_c, sum_r, den_p, den_c);

  k_final<<<(S + 7) / 8, 256, 0, stream>>>(num_p, num_c, sum_r, emb, uniq, counters,
                                           a_sp, a_dp, a_sc, a_dc, den_p, den_c, degR,
                                           vvec, Wp, Wc, Wl, Wr, outU);
  k_gather<<<(S * D + 255) / 256, 256, 0, stream>>>(s, qid, outU, out, S);
}

// Round 6
// 265.426 us; speedup vs baseline: 4.5424x; 1.1258x over previous
//
#include <hip/hip_runtime.h>

#define D 128

typedef short bf16x8 __attribute__((ext_vector_type(8)));
typedef short short4v __attribute__((ext_vector_type(4)));
typedef float f32x4 __attribute__((ext_vector_type(4)));

__device__ __forceinline__ short f2bf(float f) {
  unsigned u = __builtin_bit_cast(unsigned, f);
  unsigned r = (u + 0x7fffu + ((u >> 16) & 1u)) >> 16;
  return (short)r;
}

// ---------------- kernels ----------------

// one kernel replaces 3 memsets: qid=-1 (N), counters=0 (16), deg[3S]=0
__global__ void k_init(int* __restrict__ qid, int* __restrict__ counters,
                       int* __restrict__ deg3, int N, int S3) {
  int i = blockIdx.x * blockDim.x + threadIdx.x;
  int stride = gridDim.x * blockDim.x;
  for (int k = i; k < N; k += stride) qid[k] = -1;
  for (int k = i; k < S3; k += stride) deg3[k] = 0;
  if (i < 16) counters[i] = 0;
}

__global__ void k_build_qid(const int* __restrict__ s, int* __restrict__ qid,
                            int* __restrict__ uniq, int* __restrict__ counters, int S) {
  int i = blockIdx.x * blockDim.x + threadIdx.x;
  if (i >= S) return;
  int n = s[i];
  if (atomicCAS(&qid[n], -1, -2) == -1) {
    int u = atomicAdd(&counters[0], 1);
    uniq[u] = n;
    qid[n] = u;
  }
}

// pack Wcat = [Wp;Wc;Wl;Wr] (512x128) into bf16 per-lane MFMA B-fragments:
// wpack[((kt*8 + nt)*64 + lane)*8 + j] = Wcat[kt*32 + (lane>>4)*8 + j][nt*16 + (lane&15)]
__global__ void k_prep_w(const float* __restrict__ Wp, const float* __restrict__ Wc,
                         const float* __restrict__ Wl, const float* __restrict__ Wr,
                         short* __restrict__ wpack) {
  int idx = blockIdx.x * blockDim.x + threadIdx.x;  // 65536
  if (idx >= 16 * 8 * 64 * 8) return;
  int j    = idx & 7;
  int lane = (idx >> 3) & 63;
  int nt   = (idx >> 9) & 7;
  int kt   = idx >> 12;
  int o = kt >> 2;
  int c = (kt & 3) * 32 + (lane >> 4) * 8 + j;   // row within W_o
  int n = nt * 16 + (lane & 15);                 // output column
  const float* W = (o == 0) ? Wp : (o == 1) ? Wc : (o == 2) ? Wl : Wr;
  wpack[idx] = f2bf(W[c * D + n]);
}

// v = [Wp@asp, Wp@adp, Wc@asc, Wc@adc, bp+bc+bl]
__global__ void k_calc_v(const float* __restrict__ Wp, const float* __restrict__ asp,
                         const float* __restrict__ adp, const float* __restrict__ Wc,
                         const float* __restrict__ asc, const float* __restrict__ adc,
                         const float* __restrict__ bp, const float* __restrict__ bc,
                         const float* __restrict__ bl, float* __restrict__ v) {
  int k = threadIdx.x;  // 0..127
  float s0 = 0.f, s1 = 0.f, s2 = 0.f, s3 = 0.f;
  for (int d = 0; d < D; ++d) {
    float wp = Wp[k * D + d], wc = Wc[k * D + d];
    s0 += wp * asp[d]; s1 += wp * adp[d];
    s2 += wc * asc[d]; s3 += wc * adc[d];
  }
  v[k] = s0; v[D + k] = s1; v[2 * D + k] = s2; v[3 * D + k] = s3;
  v[4 * D + k] = bp[k] + bc[k] + bl[k];
}

// per-node attention scalars: a_* = emb[n] . v_*   (one wave per node)
__global__ void k_a(const float* __restrict__ emb, const float* __restrict__ v,
                    float* __restrict__ a_sp, float* __restrict__ a_dp,
                    float* __restrict__ a_sc, float* __restrict__ a_dc, int N) {
  int gtid = blockIdx.x * blockDim.x + threadIdx.x;
  int node = gtid >> 6;
  int lane = threadIdx.x & 63;
  if (node >= N) return;
  float2 x2 = ((const float2*)(emb + (size_t)node * D))[lane];
  float2 v0 = ((const float2*)(v))[lane];
  float2 v1 = ((const float2*)(v + D))[lane];
  float2 v2 = ((const float2*)(v + 2 * D))[lane];
  float2 v3 = ((const float2*)(v + 3 * D))[lane];
  float s0 = x2.x * v0.x + x2.y * v0.y;
  float s1 = x2.x * v1.x + x2.y * v1.y;
  float s2 = x2.x * v2.x + x2.y * v2.y;
  float s3 = x2.x * v3.x + x2.y * v3.y;
  for (int o = 32; o > 0; o >>= 1) {
    s0 += __shfl_down(s0, o);
    s1 += __shfl_down(s1, o);
    s2 += __shfl_down(s2, o);
    s3 += __shfl_down(s3, o);
  }
  if (lane == 0) { a_sp[node] = s0; a_dp[node] = s1; a_sc[node] = s2; a_dc[node] = s3; }
}

// unified filter (blockIdx.y = relation): compact {src,u}, count deg[u].
__global__ void __launch_bounds__(1024) k_filter(
    const int* __restrict__ eiP, const int* __restrict__ eiC, const int* __restrict__ eiR,
    const int* __restrict__ qid,
    int2* __restrict__ lsuP, int2* __restrict__ lsuC, int2* __restrict__ lsuR,
    int* __restrict__ degP, int* __restrict__ degC, int* __restrict__ degR,
    int* __restrict__ counters, int E) {
  int rel = blockIdx.y;
  const int* ei = (rel == 0) ? eiP : (rel == 1) ? eiC : eiR;
  int2* lsu     = (rel == 0) ? lsuP : (rel == 1) ? lsuC : lsuR;
  int* deg      = (rel == 0) ? degP : (rel == 1) ? degC : degR;
  int* cnt      = counters + 1 + rel;

  int e = blockIdx.x * 1024 + threadIdx.x;
  bool active = false;
  int src = 0, u = 0;
  if (e < E) {
    int dst = ei[E + e];
    u = qid[dst];
    if (u >= 0) { src = ei[e]; active = true; }
  }
  unsigned long long mask = __ballot(active);
  int lane = threadIdx.x & 63;
  int wid = threadIdx.x >> 6;           // 0..15
  __shared__ int wbase[16];
  if (lane == 0) wbase[wid] = __popcll(mask);
  __syncthreads();
  if (threadIdx.x == 0) {
    int tot = 0, pref[16];
#pragma unroll
    for (int i = 0; i < 16; ++i) { pref[i] = tot; tot += wbase[i]; }
    int b = atomicAdd(cnt, tot);
#pragma unroll
    for (int i = 0; i < 16; ++i) wbase[i] = b + pref[i];
  }
  __syncthreads();
  if (active) {
    int pos = wbase[wid] + __popcll(mask & ((1ULL << lane) - 1));
    int2 su; su.x = src; su.y = u;
    lsu[pos] = su;
    atomicAdd(&deg[u], 1);
  }
}

// exclusive scan of deg -> rowoff (+ working cursor copy). blockIdx.x = relation.
__global__ void __launch_bounds__(1024) k_scan(
    const int* __restrict__ degP, const int* __restrict__ degC, const int* __restrict__ degR,
    int* __restrict__ roffP, int* __restrict__ roffC, int* __restrict__ roffR,
    int* __restrict__ curP, int* __restrict__ curC, int* __restrict__ curR,
    const int* __restrict__ counters) {
  int rel = blockIdx.x;
  const int* deg = (rel == 0) ? degP : (rel == 1) ? degC : degR;
  int* roff      = (rel == 0) ? roffP : (rel == 1) ? roffC : roffR;
  int* cur       = (rel == 0) ? curP : (rel == 1) ? curC : curR;
  int U = counters[0];
  __shared__ int ssum[1024];
  int t = threadIdx.x;
  int base = t * 16;
  int vals[16];
  int s = 0;
#pragma unroll
  for (int i = 0; i < 16; ++i) {
    int idx = base + i;
    int v = (idx < U) ? deg[idx] : 0;
    vals[i] = s; s += v;
  }
  ssum[t] = s;
  __syncthreads();
  for (int off = 1; off < 1024; off <<= 1) {
    int v = (t >= off) ? ssum[t - off] : 0;
    __syncthreads();
    ssum[t] += v;
    __syncthreads();
  }
  int pre = (t == 0) ? 0 : ssum[t - 1];
#pragma unroll
  for (int i = 0; i < 16; ++i) {
    int idx = base + i;
    if (idx < U) { int o = pre + vals[i]; roff[idx] = o; cur[idx] = o; }
  }
}

// scatter compact edges into CSR segments. blockIdx.y = relation.
__global__ void k_scatter(
    const int2* __restrict__ lsuP, const int2* __restrict__ lsuC, const int2* __restrict__ lsuR,
    int* __restrict__ csrP, int* __restrict__ csrC, int* __restrict__ csrR,
    int* __restrict__ curP, int* __restrict__ curC, int* __restrict__ curR,
    const int* __restrict__ counters) {
  int rel = blockIdx.y;
  const int2* lsu = (rel == 0) ? lsuP : (rel == 1) ? lsuC : lsuR;
  int* csr        = (rel == 0) ? csrP : (rel == 1) ? csrC : csrR;
  int* cur        = (rel == 0) ? curP : (rel == 1) ? curC : curR;
  int n = counters[1 + rel];
  for (int i = blockIdx.x * blockDim.x + threadIdx.x; i < n;
       i += gridDim.x * blockDim.x) {
    int2 su = lsu[i];
    int pos = atomicAdd(&cur[su.y], 1);
    csr[pos] = su.x;
  }
}

// one wave per (u, relation): register accumulation, single row store. No atomics.
__global__ void __launch_bounds__(256) k_accum(
    const int* __restrict__ csrP, const int* __restrict__ csrC, const int* __restrict__ csrR,
    const int* __restrict__ roffP, const int* __restrict__ roffC, const int* __restrict__ roffR,
    const int* __restrict__ degP, const int* __restrict__ degC, const int* __restrict__ degR,
    const float* __restrict__ a_sp, const float* __restrict__ a_dp,
    const float* __restrict__ a_sc, const float* __restrict__ a_dc,
    const float* __restrict__ emb, const int* __restrict__ uniq,
    const int* __restrict__ counters,
    float* __restrict__ num_p, float* __restrict__ num_c, float* __restrict__ sum_r,
    float* __restrict__ den_p, float* __restrict__ den_c) {
  int U = counters[0];
  int u = blockIdx.x * 4 + (threadIdx.x >> 6);
  if (u >= U) return;
  int lane = threadIdx.x & 63;
  int rel = blockIdx.y;
  const int* csr  = (rel == 0) ? csrP : (rel == 1) ? csrC : csrR;
  const int* roff = (rel == 0) ? roffP : (rel == 1) ? roffC : roffR;
  const int* deg  = (rel == 0) ? degP : (rel == 1) ? degC : degR;
  float* num      = (rel == 0) ? num_p : (rel == 1) ? num_c : sum_r;

  int start = roff[u];
  int m = deg[u];
  float2 acc; acc.x = 0.f; acc.y = 0.f;

  if (rel == 2) {
    for (int c = 0; c < m; c += 64) {
      int mm = min(64, m - c);
      int srcl = (lane < mm) ? csr[start + c + lane] : 0;
      for (int i = 0; i < mm; ++i) {
        int si = __shfl(srcl, i);
        float2 x2 = ((const float2*)(emb + (size_t)si * D))[lane];
        acc.x += x2.x; acc.y += x2.y;
      }
    }
  } else {
    const float* a_s = (rel == 0) ? a_sp : a_sc;
    const float* a_d = (rel == 0) ? a_dp : a_dc;
    int n = uniq[u];
    float adn = a_d[n];
    float denl = 0.f;
    for (int c = 0; c < m; c += 64) {
      int mm = min(64, m - c);
      int srcl = (lane < mm) ? csr[start + c + lane] : 0;
      float wl = 0.f;
      if (lane < mm) {
        float t = a_s[srcl] + adn;
        t = t >= 0.f ? t : 0.2f * t;
        wl = __expf(t);
      }
      denl += wl;
      for (int i = 0; i < mm; ++i) {
        int si = __shfl(srcl, i);
        float wi = __shfl(wl, i);
        float2 x2 = ((const float2*)(emb + (size_t)si * D))[lane];
        acc.x += wi * x2.x; acc.y += wi * x2.y;
      }
    }
    for (int o = 32; o > 0; o >>= 1) denl += __shfl_down(denl, o);
    if (lane == 0) { ((rel == 0) ? den_p : den_c)[u] = denl; }
  }
  ((float2*)(num + (size_t)u * D))[lane] = acc;
}

// fused final via MFMA: out[u] = ([zP|zC|zR|x] @ Wcat) / 3 + bias/3
// 16 u-rows per block; Z staged to LDS in bf16 A-fragment layout;
// wave w computes n-tiles {2w, 2w+1}.
__global__ void __launch_bounds__(256) k_final(
    const float* __restrict__ num_p, const float* __restrict__ num_c,
    const float* __restrict__ sum_r, const float* __restrict__ emb,
    const int* __restrict__ uniq, const int* __restrict__ counters,
    const float* __restrict__ a_sp, const float* __restrict__ a_dp,
    const float* __restrict__ a_sc, const float* __restrict__ a_dc,
    const float* __restrict__ den_p, const float* __restrict__ den_c,
    const int* __restrict__ deg_r, const float* __restrict__ vvec,
    const short* __restrict__ wpack, float* __restrict__ outU) {
  __shared__ short A_lds[16 * 64 * 8];   // 16 KB
  int U = counters[0];
  int u0 = blockIdx.x * 16;
  if (u0 >= U) return;
  int tid = threadIdx.x;

  // staging: thread t -> row m = t>>4, col-octet (t&15): 8 cols per operand
  {
    int m = tid >> 4;
    int oc = tid & 15;
    int u = u0 + m;
    int uu = (u < U) ? u : u0;
    int n = uniq[uu];
    float tP = a_sp[n] + a_dp[n]; tP = tP >= 0.f ? tP : 0.2f * tP;
    float wP = __expf(tP);
    float rP = 1.f / (den_p[uu] + wP);
    float tC = a_sc[n] + a_dc[n]; tC = tC >= 0.f ? tC : 0.2f * tC;
    float wC = __expf(tC);
    float rC = 1.f / (den_c[uu] + wC);
    float dg = (float)deg_r[uu]; if (dg < 1.f) dg = 1.f;
    float rdeg = 1.f / dg;
#pragma unroll
    for (int half = 0; half < 2; ++half) {
      int c4 = oc * 8 + half * 4;
      int q = (c4 >> 3) & 3;
      int j0 = c4 & 7;                   // 0 or 4
      int ktc = c4 >> 5;
      float4 e4  = *(const float4*)(emb   + (size_t)n  * D + c4);
      float4 np4 = *(const float4*)(num_p + (size_t)uu * D + c4);
      float4 nc4 = *(const float4*)(num_c + (size_t)uu * D + c4);
      float4 sr4 = *(const float4*)(sum_r + (size_t)uu * D + c4);
      float4 z[4];
      z[0].x = (np4.x + wP * e4.x) * rP; z[0].y = (np4.y + wP * e4.y) * rP;
      z[0].z = (np4.z + wP * e4.z) * rP; z[0].w = (np4.w + wP * e4.w) * rP;
      z[1].x = (nc4.x + wC * e4.x) * rC; z[1].y = (nc4.y + wC * e4.y) * rC;
      z[1].z = (nc4.z + wC * e4.z) * rC; z[1].w = (nc4.w + wC * e4.w) * rC;
      z[2].x = sr4.x * rdeg; z[2].y = sr4.y * rdeg;
      z[2].z = sr4.z * rdeg; z[2].w = sr4.w * rdeg;
      z[3] = e4;
#pragma unroll
      for (int o = 0; o < 4; ++o) {
        int kt = o * 4 + ktc;
        short4v s4;
        s4.x = f2bf(z[o].x); s4.y = f2bf(z[o].y);
        s4.z = f2bf(z[o].z); s4.w = f2bf(z[o].w);
        *(short4v*)&A_lds[(kt * 64 + q * 16 + m) * 8 + j0] = s4;
      }
    }
  }
  __syncthreads();

  int w = tid >> 6;
  int lane = tid & 63;
  f32x4 acc0 = {0.f, 0.f, 0.f, 0.f};
  f32x4 acc1 = {0.f, 0.f, 0.f, 0.f};
  const bf16x8* wp = (const bf16x8*)wpack;
#pragma unroll
  for (int kt = 0; kt < 16; ++kt) {
    bf16x8 a  = *(const bf16x8*)&A_lds[(kt * 64 + lane) * 8];
    bf16x8 b0 = wp[(kt * 8 + 2 * w) * 64 + lane];
    bf16x8 b1 = wp[(kt * 8 + 2 * w + 1) * 64 + lane];
    acc0 = __builtin_amdgcn_mfma_f32_16x16x32_bf16(a, b0, acc0, 0, 0, 0);
    acc1 = __builtin_amdgcn_mfma_f32_16x16x32_bf16(a, b1, acc1, 0, 0, 0);
  }

  int col0 = 2 * w * 16 + (lane & 15);
  int col1 = col0 + 16;
  int r0 = (lane >> 4) * 4;
  float b0v = vvec[4 * D + col0] * (1.f / 3.f);
  float b1v = vvec[4 * D + col1] * (1.f / 3.f);
#pragma unroll
  for (int reg = 0; reg < 4; ++reg) {
    int u = u0 + r0 + reg;
    if (u < U) {
      outU[(size_t)u * D + col0] = acc0[reg] * (1.f / 3.f) + b0v;
      outU[(size_t)u * D + col1] = acc1[reg] * (1.f / 3.f) + b1v;
    }
  }
}

// pure gather (bias and /3 already folded into outU)
__global__ void k_gather(const int* __restrict__ s, const int* __restrict__ qid,
                         const float* __restrict__ outU, float* __restrict__ out, int S) {
  int idx = blockIdx.x * blockDim.x + threadIdx.x;
  if (idx >= S * D) return;
  int i = idx >> 7;
  int d = idx & (D - 1);
  int u = qid[s[i]];
  out[idx] = outU[(size_t)u * D + d];
}

// ---------------- launch ----------------

extern "C" void kernel_launch(void* const* d_in, const int* in_sizes, int n_in,
                              void* d_out, int out_size, void* d_ws, size_t ws_size,
                              hipStream_t stream) {
  const int*   s   = (const int*)d_in[0];
  const int*   eip = (const int*)d_in[3];
  const int*   eic = (const int*)d_in[4];
  const int*   eir = (const int*)d_in[5];
  const float* emb = (const float*)d_in[6];
  const float* Wp  = (const float*)d_in[7];
  const float* asp = (const float*)d_in[8];
  const float* adp = (const float*)d_in[9];
  const float* bp  = (const float*)d_in[10];
  const float* Wc  = (const float*)d_in[11];
  const float* asc = (const float*)d_in[12];
  const float* adc = (const float*)d_in[13];
  const float* bc  = (const float*)d_in[14];
  const float* Wl  = (const float*)d_in[15];
  const float* bl  = (const float*)d_in[16];
  const float* Wr  = (const float*)d_in[17];
  float* out = (float*)d_out;

  const int S = in_sizes[0];
  const int E = in_sizes[3] / 2;
  const int N = in_sizes[6] / D;

  char* base = (char*)d_ws;
  size_t off = 0;
  auto carve = [&](size_t bytes) -> char* {
    char* q = base + off;
    off += (bytes + 255) & ~(size_t)255;
    return q;
  };
  float* a_sp     = (float*)carve((size_t)N * 4);
  float* a_dp     = (float*)carve((size_t)N * 4);
  float* a_sc     = (float*)carve((size_t)N * 4);
  float* a_dc     = (float*)carve((size_t)N * 4);
  int*   qid      = (int*)carve((size_t)N * 4);
  int*   uniq     = (int*)carve((size_t)S * 4);
  int*   counters = (int*)carve(64);                    // [0]=U [1]=cntP [2]=cntC [3]=cntR
  float* vvec     = (float*)carve(5 * D * 4);
  short* wpack    = (short*)carve((size_t)16 * 8 * 64 * 8 * 2);   // 128 KB
  float* num_p    = (float*)carve((size_t)S * D * 4);
  float* den_p    = (float*)carve((size_t)S * 4);
  float* num_c    = (float*)carve((size_t)S * D * 4);
  float* den_c    = (float*)carve((size_t)S * 4);
  float* sum_r    = (float*)carve((size_t)S * D * 4);
  float* outU     = (float*)carve((size_t)S * D * 4);
  int*   degP     = (int*)carve((size_t)S * 4);         // degP/C/R contiguous
  int*   degC     = (int*)carve((size_t)S * 4);
  int*   degR     = (int*)carve((size_t)S * 4);
  int*   roffP    = (int*)carve((size_t)S * 4);
  int*   roffC    = (int*)carve((size_t)S * 4);
  int*   roffR    = (int*)carve((size_t)S * 4);
  int*   curP     = (int*)carve((size_t)S * 4);
  int*   curC     = (int*)carve((size_t)S * 4);
  int*   curR     = (int*)carve((size_t)S * 4);
  int2*  lsuP     = (int2*)carve((size_t)E * 8);
  int2*  lsuC     = (int2*)carve((size_t)E * 8);
  int2*  lsuR     = (int2*)carve((size_t)E * 8);
  int*   csrP     = (int*)carve((size_t)E * 4);
  int*   csrC     = (int*)carve((size_t)E * 4);
  int*   csrR     = (int*)carve((size_t)E * 4);
  (void)ws_size; (void)n_in; (void)out_size;

  k_init<<<208, 512, 0, stream>>>(qid, counters, degP, N, 3 * S);
  k_prep_w<<<256, 256, 0, stream>>>(Wp, Wc, Wl, Wr, wpack);

  k_build_qid<<<(S + 255) / 256, 256, 0, stream>>>(s, qid, uniq, counters, S);
  k_calc_v<<<1, 128, 0, stream>>>(Wp, asp, adp, Wc, asc, adc, bp, bc, bl, vvec);
  k_a<<<(N + 3) / 4, 256, 0, stream>>>(emb, vvec, a_sp, a_dp, a_sc, a_dc, N);

  const int FB = (E + 1023) / 1024;
  k_filter<<<dim3(FB, 3), 1024, 0, stream>>>(eip, eic, eir, qid, lsuP, lsuC, lsuR,
                                             degP, degC, degR, counters, E);
  k_scan<<<3, 1024, 0, stream>>>(degP, degC, degR, roffP, roffC, roffR,
                                 curP, curC, curR, counters);
  k_scatter<<<dim3(128, 3), 256, 0, stream>>>(lsuP, lsuC, lsuR, csrP, csrC, csrR,
                                              curP, curC, curR, counters);
  k_accum<<<dim3((S + 3) / 4, 3), 256, 0, stream>>>(
      csrP, csrC, csrR, roffP, roffC, roffR, degP, degC, degR,
      a_sp, a_dp, a_sc, a_dc, emb, uniq, counters,
      num_p, num_c, sum_r, den_p, den_c);

  k_final<<<(S + 15) / 16, 256, 0, stream>>>(num_p, num_c, sum_r, emb, uniq, counters,
                                             a_sp, a_dp, a_sc, a_dc, den_p, den_c, degR,
                                             vvec, wpack, outU);
  k_gather<<<(S * D + 255) / 256, 256, 0, stream>>>(s, qid, outU, out, S);
}

// Round 7
// 218.873 us; speedup vs baseline: 5.5085x; 1.2127x over previous
//
#include <hip/hip_runtime.h>

#define D 128
#define CAP 64
#define OVF_CAP 1024

typedef short bf16x8 __attribute__((ext_vector_type(8)));
typedef short short4v __attribute__((ext_vector_type(4)));
typedef float f32x4 __attribute__((ext_vector_type(4)));

__device__ __forceinline__ short f2bf(float f) {
  unsigned u = __builtin_bit_cast(unsigned, f);
  unsigned r = (u + 0x7fffu + ((u >> 16) & 1u)) >> 16;
  return (short)r;
}

// ---------------- kernels ----------------

// setup: qid=-1, deg3=0, counters=0, pack Wcat->bf16 fragments, calc_v (block 0)
__global__ void k_setup(const float* __restrict__ Wp, const float* __restrict__ asp,
                        const float* __restrict__ adp, const float* __restrict__ Wc,
                        const float* __restrict__ asc, const float* __restrict__ adc,
                        const float* __restrict__ bp, const float* __restrict__ bc,
                        const float* __restrict__ bl, const float* __restrict__ Wl,
                        const float* __restrict__ Wr,
                        float* __restrict__ v, short* __restrict__ wpack,
                        int* __restrict__ qid, int* __restrict__ counters,
                        int* __restrict__ deg3, int N, int S3) {
  int i = blockIdx.x * blockDim.x + threadIdx.x;
  int stride = gridDim.x * blockDim.x;
  for (int k = i; k < N; k += stride) qid[k] = -1;
  for (int k = i; k < S3; k += stride) deg3[k] = 0;
  if (i < 16) counters[i] = 0;

  // wpack[((kt*8+nt)*64+lane)*8+j] = Wcat[kt*32+(lane>>4)*8+j][nt*16+(lane&15)]
  for (int idx = i; idx < 16 * 8 * 64 * 8; idx += stride) {
    int j    = idx & 7;
    int lane = (idx >> 3) & 63;
    int nt   = (idx >> 9) & 7;
    int kt   = idx >> 12;
    int o = kt >> 2;
    int c = (kt & 3) * 32 + (lane >> 4) * 8 + j;
    int n = nt * 16 + (lane & 15);
    const float* W = (o == 0) ? Wp : (o == 1) ? Wc : (o == 2) ? Wl : Wr;
    wpack[idx] = f2bf(W[c * D + n]);
  }

  if (blockIdx.x == 0 && threadIdx.x < 128) {
    int k = threadIdx.x;
    float s0 = 0.f, s1 = 0.f, s2 = 0.f, s3 = 0.f;
    for (int d = 0; d < D; ++d) {
      float wp = Wp[k * D + d], wc = Wc[k * D + d];
      s0 += wp * asp[d]; s1 += wp * adp[d];
      s2 += wc * asc[d]; s3 += wc * adc[d];
    }
    v[k] = s0; v[D + k] = s1; v[2 * D + k] = s2; v[3 * D + k] = s3;
    v[4 * D + k] = bp[k] + bc[k] + bl[k];
  }
}

// build_qid (first S threads) + per-node attention scalars (one wave per node)
__global__ void k_pre(const int* __restrict__ s, int* __restrict__ qid,
                      int* __restrict__ uniq, int* __restrict__ counters, int S,
                      const float* __restrict__ emb, const float* __restrict__ v,
                      float* __restrict__ a_sp, float* __restrict__ a_dp,
                      float* __restrict__ a_sc, float* __restrict__ a_dc, int N) {
  int gtid = blockIdx.x * blockDim.x + threadIdx.x;
  if (gtid < S) {
    int n = s[gtid];
    if (atomicCAS(&qid[n], -1, -2) == -1) {
      int u = atomicAdd(&counters[0], 1);
      uniq[u] = n;
      qid[n] = u;
    }
  }
  int node = gtid >> 6;
  int lane = threadIdx.x & 63;
  if (node >= N) return;
  float2 x2 = ((const float2*)(emb + (size_t)node * D))[lane];
  float2 v0 = ((const float2*)(v))[lane];
  float2 v1 = ((const float2*)(v + D))[lane];
  float2 v2 = ((const float2*)(v + 2 * D))[lane];
  float2 v3 = ((const float2*)(v + 3 * D))[lane];
  float s0 = x2.x * v0.x + x2.y * v0.y;
  float s1 = x2.x * v1.x + x2.y * v1.y;
  float s2 = x2.x * v2.x + x2.y * v2.y;
  float s3 = x2.x * v3.x + x2.y * v3.y;
  for (int o = 32; o > 0; o >>= 1) {
    s0 += __shfl_down(s0, o);
    s1 += __shfl_down(s1, o);
    s2 += __shfl_down(s2, o);
    s3 += __shfl_down(s3, o);
  }
  if (lane == 0) { a_sp[node] = s0; a_dp[node] = s1; a_sc[node] = s2; a_dc[node] = s3; }
}

// direct-bucket filter (blockIdx.y = relation): bucket[u*CAP+pos]=src, deg[u]++
__global__ void __launch_bounds__(256) k_filter(
    const int* __restrict__ eiP, const int* __restrict__ eiC, const int* __restrict__ eiR,
    const int* __restrict__ qid,
    int* __restrict__ bktP, int* __restrict__ bktC, int* __restrict__ bktR,
    int* __restrict__ degP, int* __restrict__ degC, int* __restrict__ degR,
    int2* __restrict__ ovf, int* __restrict__ counters, int E) {
  int rel = blockIdx.y;
  const int* ei = (rel == 0) ? eiP : (rel == 1) ? eiC : eiR;
  int* bkt      = (rel == 0) ? bktP : (rel == 1) ? bktC : bktR;
  int* deg      = (rel == 0) ? degP : (rel == 1) ? degC : degR;
  int e = blockIdx.x * 256 + threadIdx.x;
  if (e >= E) return;
  int dst = ei[E + e];
  int u = qid[dst];
  if (u < 0) return;
  int src = ei[e];
  int pos = atomicAdd(&deg[u], 1);
  if (pos < CAP) {
    bkt[u * CAP + pos] = src;
  } else {
    int o = atomicAdd(&counters[4 + rel], 1);
    if (o < OVF_CAP) { int2 t; t.x = src; t.y = u; ovf[rel * OVF_CAP + o] = t; }
  }
}

// one wave per (u, relation): register accumulation, single row store. No atomics.
__global__ void __launch_bounds__(256) k_accum(
    const int* __restrict__ bktP, const int* __restrict__ bktC, const int* __restrict__ bktR,
    const int* __restrict__ degP, const int* __restrict__ degC, const int* __restrict__ degR,
    const float* __restrict__ a_sp, const float* __restrict__ a_dp,
    const float* __restrict__ a_sc, const float* __restrict__ a_dc,
    const float* __restrict__ emb, const int* __restrict__ uniq,
    const int* __restrict__ counters, const int2* __restrict__ ovf,
    float* __restrict__ num_p, float* __restrict__ num_c, float* __restrict__ sum_r,
    float* __restrict__ den_p, float* __restrict__ den_c) {
  int U = counters[0];
  int u = blockIdx.x * 4 + (threadIdx.x >> 6);
  if (u >= U) return;
  int lane = threadIdx.x & 63;
  int rel = blockIdx.y;
  const int* bkt = (rel == 0) ? bktP : (rel == 1) ? bktC : bktR;
  const int* deg = (rel == 0) ? degP : (rel == 1) ? degC : degR;
  float* num     = (rel == 0) ? num_p : (rel == 1) ? num_c : sum_r;

  int m = deg[u];
  int mc = (m < CAP) ? m : CAP;
  int L = counters[4 + rel];
  const int* b0 = bkt + u * CAP;
  float2 acc; acc.x = 0.f; acc.y = 0.f;

  if (rel == 2) {
    for (int c = 0; c < mc; c += 64) {
      int mm = min(64, mc - c);
      int srcl = (lane < mm) ? b0[c + lane] : 0;
      for (int i = 0; i < mm; ++i) {
        int si = __shfl(srcl, i);
        float2 x2 = ((const float2*)(emb + (size_t)si * D))[lane];
        acc.x += x2.x; acc.y += x2.y;
      }
    }
    for (int l = 0; l < L; ++l) {
      int2 ov = ovf[2 * OVF_CAP + l];
      if (ov.y == u) {
        float2 x2 = ((const float2*)(emb + (size_t)ov.x * D))[lane];
        acc.x += x2.x; acc.y += x2.y;
      }
    }
  } else {
    const float* a_s = (rel == 0) ? a_sp : a_sc;
    const float* a_d = (rel == 0) ? a_dp : a_dc;
    int n = uniq[u];
    float adn = a_d[n];
    float denl = 0.f, denx = 0.f;
    for (int c = 0; c < mc; c += 64) {
      int mm = min(64, mc - c);
      int srcl = (lane < mm) ? b0[c + lane] : 0;
      float wl = 0.f;
      if (lane < mm) {
        float t = a_s[srcl] + adn;
        t = t >= 0.f ? t : 0.2f * t;
        wl = __expf(t);
      }
      denl += wl;
      for (int i = 0; i < mm; ++i) {
        int si = __shfl(srcl, i);
        float wi = __shfl(wl, i);
        float2 x2 = ((const float2*)(emb + (size_t)si * D))[lane];
        acc.x += wi * x2.x; acc.y += wi * x2.y;
      }
    }
    for (int l = 0; l < L; ++l) {
      int2 ov = ovf[rel * OVF_CAP + l];
      if (ov.y == u) {
        float t = a_s[ov.x] + adn;
        t = t >= 0.f ? t : 0.2f * t;
        float w = __expf(t);
        float2 x2 = ((const float2*)(emb + (size_t)ov.x * D))[lane];
        acc.x += w * x2.x; acc.y += w * x2.y;
        if (lane == 0) denx += w;
      }
    }
    for (int o = 32; o > 0; o >>= 1) denl += __shfl_down(denl, o);
    if (lane == 0) { ((rel == 0) ? den_p : den_c)[u] = denl + denx; }
  }
  ((float2*)(num + (size_t)u * D))[lane] = acc;
}

// fused final via MFMA: out[u] = ([zP|zC|zR|x] @ Wcat) / 3 + bias/3
__global__ void __launch_bounds__(256) k_final(
    const float* __restrict__ num_p, const float* __restrict__ num_c,
    const float* __restrict__ sum_r, const float* __restrict__ emb,
    const int* __restrict__ uniq, const int* __restrict__ counters,
    const float* __restrict__ a_sp, const float* __restrict__ a_dp,
    const float* __restrict__ a_sc, const float* __restrict__ a_dc,
    const float* __restrict__ den_p, const float* __restrict__ den_c,
    const int* __restrict__ deg_r, const float* __restrict__ vvec,
    const short* __restrict__ wpack, float* __restrict__ outU) {
  __shared__ short A_lds[16 * 64 * 8];   // 16 KB
  int U = counters[0];
  int u0 = blockIdx.x * 16;
  if (u0 >= U) return;
  int tid = threadIdx.x;

  {
    int m = tid >> 4;
    int oc = tid & 15;
    int u = u0 + m;
    int uu = (u < U) ? u : u0;
    int n = uniq[uu];
    float tP = a_sp[n] + a_dp[n]; tP = tP >= 0.f ? tP : 0.2f * tP;
    float wP = __expf(tP);
    float rP = 1.f / (den_p[uu] + wP);
    float tC = a_sc[n] + a_dc[n]; tC = tC >= 0.f ? tC : 0.2f * tC;
    float wC = __expf(tC);
    float rC = 1.f / (den_c[uu] + wC);
    float dg = (float)deg_r[uu]; if (dg < 1.f) dg = 1.f;
    float rdeg = 1.f / dg;
#pragma unroll
    for (int half = 0; half < 2; ++half) {
      int c4 = oc * 8 + half * 4;
      int q = (c4 >> 3) & 3;
      int j0 = c4 & 7;
      int ktc = c4 >> 5;
      float4 e4  = *(const float4*)(emb   + (size_t)n  * D + c4);
      float4 np4 = *(const float4*)(num_p + (size_t)uu * D + c4);
      float4 nc4 = *(const float4*)(num_c + (size_t)uu * D + c4);
      float4 sr4 = *(const float4*)(sum_r + (size_t)uu * D + c4);
      float4 z[4];
      z[0].x = (np4.x + wP * e4.x) * rP; z[0].y = (np4.y + wP * e4.y) * rP;
      z[0].z = (np4.z + wP * e4.z) * rP; z[0].w = (np4.w + wP * e4.w) * rP;
      z[1].x = (nc4.x + wC * e4.x) * rC; z[1].y = (nc4.y + wC * e4.y) * rC;
      z[1].z = (nc4.z + wC * e4.z) * rC; z[1].w = (nc4.w + wC * e4.w) * rC;
      z[2].x = sr4.x * rdeg; z[2].y = sr4.y * rdeg;
      z[2].z = sr4.z * rdeg; z[2].w = sr4.w * rdeg;
      z[3] = e4;
#pragma unroll
      for (int o = 0; o < 4; ++o) {
        int kt = o * 4 + ktc;
        short4v s4;
        s4.x = f2bf(z[o].x); s4.y = f2bf(z[o].y);
        s4.z = f2bf(z[o].z); s4.w = f2bf(z[o].w);
        *(short4v*)&A_lds[(kt * 64 + q * 16 + m) * 8 + j0] = s4;
      }
    }
  }
  __syncthreads();

  int w = tid >> 6;
  int lane = tid & 63;
  f32x4 acc0 = {0.f, 0.f, 0.f, 0.f};
  f32x4 acc1 = {0.f, 0.f, 0.f, 0.f};
  const bf16x8* wp = (const bf16x8*)wpack;
#pragma unroll
  for (int kt = 0; kt < 16; ++kt) {
    bf16x8 a  = *(const bf16x8*)&A_lds[(kt * 64 + lane) * 8];
    bf16x8 b0 = wp[(kt * 8 + 2 * w) * 64 + lane];
    bf16x8 b1 = wp[(kt * 8 + 2 * w + 1) * 64 + lane];
    acc0 = __builtin_amdgcn_mfma_f32_16x16x32_bf16(a, b0, acc0, 0, 0, 0);
    acc1 = __builtin_amdgcn_mfma_f32_16x16x32_bf16(a, b1, acc1, 0, 0, 0);
  }

  int col0 = 2 * w * 16 + (lane & 15);
  int col1 = col0 + 16;
  int r0 = (lane >> 4) * 4;
  float b0v = vvec[4 * D + col0] * (1.f / 3.f);
  float b1v = vvec[4 * D + col1] * (1.f / 3.f);
#pragma unroll
  for (int reg = 0; reg < 4; ++reg) {
    int u = u0 + r0 + reg;
    if (u < U) {
      outU[(size_t)u * D + col0] = acc0[reg] * (1.f / 3.f) + b0v;
      outU[(size_t)u * D + col1] = acc1[reg] * (1.f / 3.f) + b1v;
    }
  }
}

// pure gather (bias and /3 already folded into outU)
__global__ void k_gather(const int* __restrict__ s, const int* __restrict__ qid,
                         const float* __restrict__ outU, float* __restrict__ out, int S) {
  int idx = blockIdx.x * blockDim.x + threadIdx.x;
  if (idx >= S * D) return;
  int i = idx >> 7;
  int d = idx & (D - 1);
  int u = qid[s[i]];
  out[idx] = outU[(size_t)u * D + d];
}

// ---------------- launch ----------------

extern "C" void kernel_launch(void* const* d_in, const int* in_sizes, int n_in,
                              void* d_out, int out_size, void* d_ws, size_t ws_size,
                              hipStream_t stream) {
  const int*   s   = (const int*)d_in[0];
  const int*   eip = (const int*)d_in[3];
  const int*   eic = (const int*)d_in[4];
  const int*   eir = (const int*)d_in[5];
  const float* emb = (const float*)d_in[6];
  const float* Wp  = (const float*)d_in[7];
  const float* asp = (const float*)d_in[8];
  const float* adp = (const float*)d_in[9];
  const float* bp  = (const float*)d_in[10];
  const float* Wc  = (const float*)d_in[11];
  const float* asc = (const float*)d_in[12];
  const float* adc = (const float*)d_in[13];
  const float* bc  = (const float*)d_in[14];
  const float* Wl  = (const float*)d_in[15];
  const float* bl  = (const float*)d_in[16];
  const float* Wr  = (const float*)d_in[17];
  float* out = (float*)d_out;

  const int S = in_sizes[0];
  const int E = in_sizes[3] / 2;
  const int N = in_sizes[6] / D;

  char* base = (char*)d_ws;
  size_t off = 0;
  auto carve = [&](size_t bytes) -> char* {
    char* q = base + off;
    off += (bytes + 255) & ~(size_t)255;
    return q;
  };
  float* a_sp     = (float*)carve((size_t)N * 4);
  float* a_dp     = (float*)carve((size_t)N * 4);
  float* a_sc     = (float*)carve((size_t)N * 4);
  float* a_dc     = (float*)carve((size_t)N * 4);
  int*   qid      = (int*)carve((size_t)N * 4);
  int*   uniq     = (int*)carve((size_t)S * 4);
  int*   counters = (int*)carve(64);    // [0]=U [4..6]=overflow counts
  float* vvec     = (float*)carve(5 * D * 4);
  short* wpack    = (short*)carve((size_t)16 * 8 * 64 * 8 * 2);   // 128 KB
  float* num_p    = (float*)carve((size_t)S * D * 4);
  float* den_p    = (float*)carve((size_t)S * 4);
  float* num_c    = (float*)carve((size_t)S * D * 4);
  float* den_c    = (float*)carve((size_t)S * 4);
  float* sum_r    = (float*)carve((size_t)S * D * 4);
  float* outU     = (float*)carve((size_t)S * D * 4);
  int*   degP     = (int*)carve((size_t)S * 4);         // degP/C/R contiguous
  int*   degC     = (int*)carve((size_t)S * 4);
  int*   degR     = (int*)carve((size_t)S * 4);
  int*   bktP     = (int*)carve((size_t)S * CAP * 4);   // 4 MB each
  int*   bktC     = (int*)carve((size_t)S * CAP * 4);
  int*   bktR     = (int*)carve((size_t)S * CAP * 4);
  int2*  ovf      = (int2*)carve((size_t)3 * OVF_CAP * 8);
  (void)ws_size; (void)n_in; (void)out_size;

  k_setup<<<256, 256, 0, stream>>>(Wp, asp, adp, Wc, asc, adc, bp, bc, bl, Wl, Wr,
                                   vvec, wpack, qid, counters, degP, N, 3 * S);

  k_pre<<<(N * 64 + 255) / 256, 256, 0, stream>>>(s, qid, uniq, counters, S,
                                                  emb, vvec, a_sp, a_dp, a_sc, a_dc, N);

  k_filter<<<dim3((E + 255) / 256, 3), 256, 0, stream>>>(
      eip, eic, eir, qid, bktP, bktC, bktR, degP, degC, degR, ovf, counters, E);

  k_accum<<<dim3((S + 3) / 4, 3), 256, 0, stream>>>(
      bktP, bktC, bktR, degP, degC, degR,
      a_sp, a_dp, a_sc, a_dc, emb, uniq, counters, ovf,
      num_p, num_c, sum_r, den_p, den_c);

  k_final<<<(S + 15) / 16, 256, 0, stream>>>(num_p, num_c, sum_r, emb, uniq, counters,
                                             a_sp, a_dp, a_sc, a_dc, den_p, den_c, degR,
                                             vvec, wpack, outU);
  k_gather<<<(S * D + 255) / 256, 256, 0, stream>>>(s, qid, outU, out, S);
}

// Round 8
// 213.184 us; speedup vs baseline: 5.6555x; 1.0267x over previous
//
#include <hip/hip_runtime.h>

#define D 128
#define CAP 64
#define OVF_CAP 1024

typedef short bf16x8 __attribute__((ext_vector_type(8)));
typedef short short4v __attribute__((ext_vector_type(4)));
typedef float f32x4 __attribute__((ext_vector_type(4)));

__device__ __forceinline__ short f2bf(float f) {
  unsigned u = __builtin_bit_cast(unsigned, f);
  unsigned r = (u + 0x7fffu + ((u >> 16) & 1u)) >> 16;
  return (short)r;
}
__device__ __forceinline__ float bflo(unsigned r) {   // element 2*lane
  return __builtin_bit_cast(float, r << 16);
}
__device__ __forceinline__ float bfhi(unsigned r) {   // element 2*lane+1
  return __builtin_bit_cast(float, r & 0xffff0000u);
}

// ---------------- kernels ----------------

// setup: qid=-1, deg3=0, counters=0, pack Wcat->bf16 fragments, calc_v (block 0)
__global__ void k_setup(const float* __restrict__ Wp, const float* __restrict__ asp,
                        const float* __restrict__ adp, const float* __restrict__ Wc,
                        const float* __restrict__ asc, const float* __restrict__ adc,
                        const float* __restrict__ bp, const float* __restrict__ bc,
                        const float* __restrict__ bl, const float* __restrict__ Wl,
                        const float* __restrict__ Wr,
                        float* __restrict__ v, short* __restrict__ wpack,
                        int* __restrict__ qid, int* __restrict__ counters,
                        int* __restrict__ deg3, int N, int S3) {
  int i = blockIdx.x * blockDim.x + threadIdx.x;
  int stride = gridDim.x * blockDim.x;
  for (int k = i; k < N; k += stride) qid[k] = -1;
  for (int k = i; k < S3; k += stride) deg3[k] = 0;
  if (i < 16) counters[i] = 0;

  // wpack[((kt*8+nt)*64+lane)*8+j] = Wcat[kt*32+(lane>>4)*8+j][nt*16+(lane&15)]
  for (int idx = i; idx < 16 * 8 * 64 * 8; idx += stride) {
    int j    = idx & 7;
    int lane = (idx >> 3) & 63;
    int nt   = (idx >> 9) & 7;
    int kt   = idx >> 12;
    int o = kt >> 2;
    int c = (kt & 3) * 32 + (lane >> 4) * 8 + j;
    int n = nt * 16 + (lane & 15);
    const float* W = (o == 0) ? Wp : (o == 1) ? Wc : (o == 2) ? Wl : Wr;
    wpack[idx] = f2bf(W[c * D + n]);
  }

  if (blockIdx.x == 0 && threadIdx.x < 128) {
    int k = threadIdx.x;
    float s0 = 0.f, s1 = 0.f, s2 = 0.f, s3 = 0.f;
    for (int d = 0; d < D; ++d) {
      float wp = Wp[k * D + d], wc = Wc[k * D + d];
      s0 += wp * asp[d]; s1 += wp * adp[d];
      s2 += wc * asc[d]; s3 += wc * adc[d];
    }
    v[k] = s0; v[D + k] = s1; v[2 * D + k] = s2; v[3 * D + k] = s3;
    v[4 * D + k] = bp[k] + bc[k] + bl[k];
  }
}

// build_qid (first S threads) + attention scalars + bf16 emb copy (one wave/node)
__global__ void k_pre(const int* __restrict__ s, int* __restrict__ qid,
                      int* __restrict__ uniq, int* __restrict__ counters, int S,
                      const float* __restrict__ emb, const float* __restrict__ v,
                      float* __restrict__ a_sp, float* __restrict__ a_dp,
                      float* __restrict__ a_sc, float* __restrict__ a_dc,
                      unsigned* __restrict__ ebf, int N) {
  int gtid = blockIdx.x * blockDim.x + threadIdx.x;
  if (gtid < S) {
    int n = s[gtid];
    if (atomicCAS(&qid[n], -1, -2) == -1) {
      int u = atomicAdd(&counters[0], 1);
      uniq[u] = n;
      qid[n] = u;
    }
  }
  int node = gtid >> 6;
  int lane = threadIdx.x & 63;
  if (node >= N) return;
  float2 x2 = ((const float2*)(emb + (size_t)node * D))[lane];
  // bf16 copy for gather phase
  unsigned p = ((unsigned)(unsigned short)f2bf(x2.x)) |
               (((unsigned)(unsigned short)f2bf(x2.y)) << 16);
  ebf[(size_t)node * 64 + lane] = p;
  float2 v0 = ((const float2*)(v))[lane];
  float2 v1 = ((const float2*)(v + D))[lane];
  float2 v2 = ((const float2*)(v + 2 * D))[lane];
  float2 v3 = ((const float2*)(v + 3 * D))[lane];
  float s0 = x2.x * v0.x + x2.y * v0.y;
  float s1 = x2.x * v1.x + x2.y * v1.y;
  float s2 = x2.x * v2.x + x2.y * v2.y;
  float s3 = x2.x * v3.x + x2.y * v3.y;
  for (int o = 32; o > 0; o >>= 1) {
    s0 += __shfl_down(s0, o);
    s1 += __shfl_down(s1, o);
    s2 += __shfl_down(s2, o);
    s3 += __shfl_down(s3, o);
  }
  if (lane == 0) { a_sp[node] = s0; a_dp[node] = s1; a_sc[node] = s2; a_dc[node] = s3; }
}

// direct-bucket filter (blockIdx.y = relation): bucket[u*CAP+pos]=src, deg[u]++
__global__ void __launch_bounds__(256) k_filter(
    const int* __restrict__ eiP, const int* __restrict__ eiC, const int* __restrict__ eiR,
    const int* __restrict__ qid,
    int* __restrict__ bktP, int* __restrict__ bktC, int* __restrict__ bktR,
    int* __restrict__ degP, int* __restrict__ degC, int* __restrict__ degR,
    int2* __restrict__ ovf, int* __restrict__ counters, int E) {
  int rel = blockIdx.y;
  const int* ei = (rel == 0) ? eiP : (rel == 1) ? eiC : eiR;
  int* bkt      = (rel == 0) ? bktP : (rel == 1) ? bktC : bktR;
  int* deg      = (rel == 0) ? degP : (rel == 1) ? degC : degR;
  int e = blockIdx.x * 256 + threadIdx.x;
  if (e >= E) return;
  int dst = ei[E + e];
  int u = qid[dst];
  if (u < 0) return;
  int src = ei[e];
  int pos = atomicAdd(&deg[u], 1);
  if (pos < CAP) {
    bkt[u * CAP + pos] = src;
  } else {
    int o = atomicAdd(&counters[4 + rel], 1);
    if (o < OVF_CAP) { int2 t; t.x = src; t.y = u; ovf[rel * OVF_CAP + o] = t; }
  }
}

// one wave per (u, relation): bf16 gathers, 4 loads in flight, single row store.
__global__ void __launch_bounds__(256) k_accum(
    const int* __restrict__ bktP, const int* __restrict__ bktC, const int* __restrict__ bktR,
    const int* __restrict__ degP, const int* __restrict__ degC, const int* __restrict__ degR,
    const float* __restrict__ a_sp, const float* __restrict__ a_dp,
    const float* __restrict__ a_sc, const float* __restrict__ a_dc,
    const unsigned* __restrict__ ebf, const int* __restrict__ uniq,
    const int* __restrict__ counters, const int2* __restrict__ ovf,
    float* __restrict__ num_p, float* __restrict__ num_c, float* __restrict__ sum_r,
    float* __restrict__ den_p, float* __restrict__ den_c) {
  int U = counters[0];
  int u = blockIdx.x * 4 + (threadIdx.x >> 6);
  if (u >= U) return;
  int lane = threadIdx.x & 63;
  int rel = blockIdx.y;
  const int* bkt = (rel == 0) ? bktP : (rel == 1) ? bktC : bktR;
  const int* deg = (rel == 0) ? degP : (rel == 1) ? degC : degR;
  float* num     = (rel == 0) ? num_p : (rel == 1) ? num_c : sum_r;

  int m = deg[u];
  int mc = (m < CAP) ? m : CAP;   // exactly one 64-chunk
  int L = counters[4 + rel];
  if (L > OVF_CAP) L = OVF_CAP;
  const int* b0 = bkt + u * CAP;
  float2 acc; acc.x = 0.f; acc.y = 0.f;

  int srcl = (lane < mc) ? b0[lane] : 0;
  float wl = 0.f;
  bool gat = (rel != 2);
  float denl = 0.f;
  if (gat) {
    const float* a_s = (rel == 0) ? a_sp : a_sc;
    const float* a_d = (rel == 0) ? a_dp : a_dc;
    int n = uniq[u];
    float adn = a_d[n];
    if (lane < mc) {
      float t = a_s[srcl] + adn;
      t = t >= 0.f ? t : 0.2f * t;
      wl = __expf(t);
    }
    denl = wl;
  } else {
    wl = (lane < mc) ? 1.f : 0.f;
  }

  int i = 0;
  for (; i + 4 <= mc; i += 4) {
    int s0 = __shfl(srcl, i),     s1 = __shfl(srcl, i + 1);
    int s2 = __shfl(srcl, i + 2), s3 = __shfl(srcl, i + 3);
    float w0 = __shfl(wl, i),     w1 = __shfl(wl, i + 1);
    float w2 = __shfl(wl, i + 2), w3 = __shfl(wl, i + 3);
    unsigned r0 = ebf[(size_t)s0 * 64 + lane];
    unsigned r1 = ebf[(size_t)s1 * 64 + lane];
    unsigned r2 = ebf[(size_t)s2 * 64 + lane];
    unsigned r3 = ebf[(size_t)s3 * 64 + lane];
    acc.x += w0 * bflo(r0) + w1 * bflo(r1) + w2 * bflo(r2) + w3 * bflo(r3);
    acc.y += w0 * bfhi(r0) + w1 * bfhi(r1) + w2 * bfhi(r2) + w3 * bfhi(r3);
  }
  for (; i < mc; ++i) {
    int si = __shfl(srcl, i);
    float wi = __shfl(wl, i);
    unsigned r = ebf[(size_t)si * 64 + lane];
    acc.x += wi * bflo(r);
    acc.y += wi * bfhi(r);
  }

  // overflow fixup (statistically never taken: CAP=64 >> max deg)
  if (gat) {
    const float* a_s = (rel == 0) ? a_sp : a_sc;
    const float* a_d = (rel == 0) ? a_dp : a_dc;
    float adn = a_d[uniq[u]];
    float denx = 0.f;
    for (int l = 0; l < L; ++l) {
      int2 ov = ovf[rel * OVF_CAP + l];
      if (ov.y == u) {
        float t = a_s[ov.x] + adn;
        t = t >= 0.f ? t : 0.2f * t;
        float w = __expf(t);
        unsigned r = ebf[(size_t)ov.x * 64 + lane];
        acc.x += w * bflo(r); acc.y += w * bfhi(r);
        if (lane == 0) denx += w;
      }
    }
    for (int o = 32; o > 0; o >>= 1) denl += __shfl_down(denl, o);
    if (lane == 0) { ((rel == 0) ? den_p : den_c)[u] = denl + denx; }
  } else {
    for (int l = 0; l < L; ++l) {
      int2 ov = ovf[2 * OVF_CAP + l];
      if (ov.y == u) {
        unsigned r = ebf[(size_t)ov.x * 64 + lane];
        acc.x += bflo(r); acc.y += bfhi(r);
      }
    }
  }
  ((float2*)(num + (size_t)u * D))[lane] = acc;
}

// fused final via MFMA: out[u] = ([zP|zC|zR|x] @ Wcat) / 3 + bias/3
__global__ void __launch_bounds__(256) k_final(
    const float* __restrict__ num_p, const float* __restrict__ num_c,
    const float* __restrict__ sum_r, const float* __restrict__ emb,
    const int* __restrict__ uniq, const int* __restrict__ counters,
    const float* __restrict__ a_sp, const float* __restrict__ a_dp,
    const float* __restrict__ a_sc, const float* __restrict__ a_dc,
    const float* __restrict__ den_p, const float* __restrict__ den_c,
    const int* __restrict__ deg_r, const float* __restrict__ vvec,
    const short* __restrict__ wpack, float* __restrict__ outU) {
  __shared__ short A_lds[16 * 64 * 8];   // 16 KB
  int U = counters[0];
  int u0 = blockIdx.x * 16;
  if (u0 >= U) return;
  int tid = threadIdx.x;

  {
    int m = tid >> 4;
    int oc = tid & 15;
    int u = u0 + m;
    int uu = (u < U) ? u : u0;
    int n = uniq[uu];
    float tP = a_sp[n] + a_dp[n]; tP = tP >= 0.f ? tP : 0.2f * tP;
    float wP = __expf(tP);
    float rP = 1.f / (den_p[uu] + wP);
    float tC = a_sc[n] + a_dc[n]; tC = tC >= 0.f ? tC : 0.2f * tC;
    float wC = __expf(tC);
    float rC = 1.f / (den_c[uu] + wC);
    float dg = (float)deg_r[uu]; if (dg < 1.f) dg = 1.f;
    float rdeg = 1.f / dg;
#pragma unroll
    for (int half = 0; half < 2; ++half) {
      int c4 = oc * 8 + half * 4;
      int q = (c4 >> 3) & 3;
      int j0 = c4 & 7;
      int ktc = c4 >> 5;
      float4 e4  = *(const float4*)(emb   + (size_t)n  * D + c4);
      float4 np4 = *(const float4*)(num_p + (size_t)uu * D + c4);
      float4 nc4 = *(const float4*)(num_c + (size_t)uu * D + c4);
      float4 sr4 = *(const float4*)(sum_r + (size_t)uu * D + c4);
      float4 z[4];
      z[0].x = (np4.x + wP * e4.x) * rP; z[0].y = (np4.y + wP * e4.y) * rP;
      z[0].z = (np4.z + wP * e4.z) * rP; z[0].w = (np4.w + wP * e4.w) * rP;
      z[1].x = (nc4.x + wC * e4.x) * rC; z[1].y = (nc4.y + wC * e4.y) * rC;
      z[1].z = (nc4.z + wC * e4.z) * rC; z[1].w = (nc4.w + wC * e4.w) * rC;
      z[2].x = sr4.x * rdeg; z[2].y = sr4.y * rdeg;
      z[2].z = sr4.z * rdeg; z[2].w = sr4.w * rdeg;
      z[3] = e4;
#pragma unroll
      for (int o = 0; o < 4; ++o) {
        int kt = o * 4 + ktc;
        short4v s4;
        s4.x = f2bf(z[o].x); s4.y = f2bf(z[o].y);
        s4.z = f2bf(z[o].z); s4.w = f2bf(z[o].w);
        *(short4v*)&A_lds[(kt * 64 + q * 16 + m) * 8 + j0] = s4;
      }
    }
  }
  __syncthreads();

  int w = tid >> 6;
  int lane = tid & 63;
  f32x4 acc0 = {0.f, 0.f, 0.f, 0.f};
  f32x4 acc1 = {0.f, 0.f, 0.f, 0.f};
  const bf16x8* wp = (const bf16x8*)wpack;
#pragma unroll
  for (int kt = 0; kt < 16; ++kt) {
    bf16x8 a  = *(const bf16x8*)&A_lds[(kt * 64 + lane) * 8];
    bf16x8 b0 = wp[(kt * 8 + 2 * w) * 64 + lane];
    bf16x8 b1 = wp[(kt * 8 + 2 * w + 1) * 64 + lane];
    acc0 = __builtin_amdgcn_mfma_f32_16x16x32_bf16(a, b0, acc0, 0, 0, 0);
    acc1 = __builtin_amdgcn_mfma_f32_16x16x32_bf16(a, b1, acc1, 0, 0, 0);
  }

  int col0 = 2 * w * 16 + (lane & 15);
  int col1 = col0 + 16;
  int r0 = (lane >> 4) * 4;
  float b0v = vvec[4 * D + col0] * (1.f / 3.f);
  float b1v = vvec[4 * D + col1] * (1.f / 3.f);
#pragma unroll
  for (int reg = 0; reg < 4; ++reg) {
    int u = u0 + r0 + reg;
    if (u < U) {
      outU[(size_t)u * D + col0] = acc0[reg] * (1.f / 3.f) + b0v;
      outU[(size_t)u * D + col1] = acc1[reg] * (1.f / 3.f) + b1v;
    }
  }
}

// pure gather (bias and /3 already folded into outU)
__global__ void k_gather(const int* __restrict__ s, const int* __restrict__ qid,
                         const float* __restrict__ outU, float* __restrict__ out, int S) {
  int idx = blockIdx.x * blockDim.x + threadIdx.x;
  if (idx >= S * D) return;
  int i = idx >> 7;
  int d = idx & (D - 1);
  int u = qid[s[i]];
  out[idx] = outU[(size_t)u * D + d];
}

// ---------------- launch ----------------

extern "C" void kernel_launch(void* const* d_in, const int* in_sizes, int n_in,
                              void* d_out, int out_size, void* d_ws, size_t ws_size,
                              hipStream_t stream) {
  const int*   s   = (const int*)d_in[0];
  const int*   eip = (const int*)d_in[3];
  const int*   eic = (const int*)d_in[4];
  const int*   eir = (const int*)d_in[5];
  const float* emb = (const float*)d_in[6];
  const float* Wp  = (const float*)d_in[7];
  const float* asp = (const float*)d_in[8];
  const float* adp = (const float*)d_in[9];
  const float* bp  = (const float*)d_in[10];
  const float* Wc  = (const float*)d_in[11];
  const float* asc = (const float*)d_in[12];
  const float* adc = (const float*)d_in[13];
  const float* bc  = (const float*)d_in[14];
  const float* Wl  = (const float*)d_in[15];
  const float* bl  = (const float*)d_in[16];
  const float* Wr  = (const float*)d_in[17];
  float* out = (float*)d_out;

  const int S = in_sizes[0];
  const int E = in_sizes[3] / 2;
  const int N = in_sizes[6] / D;

  char* base = (char*)d_ws;
  size_t off = 0;
  auto carve = [&](size_t bytes) -> char* {
    char* q = base + off;
    off += (bytes + 255) & ~(size_t)255;
    return q;
  };
  float*    a_sp     = (float*)carve((size_t)N * 4);
  float*    a_dp     = (float*)carve((size_t)N * 4);
  float*    a_sc     = (float*)carve((size_t)N * 4);
  float*    a_dc     = (float*)carve((size_t)N * 4);
  int*      qid      = (int*)carve((size_t)N * 4);
  unsigned* ebf      = (unsigned*)carve((size_t)N * 64 * 4);   // 25.6 MB bf16 emb
  int*      uniq     = (int*)carve((size_t)S * 4);
  int*      counters = (int*)carve(64);    // [0]=U [4..6]=overflow counts
  float*    vvec     = (float*)carve(5 * D * 4);
  short*    wpack    = (short*)carve((size_t)16 * 8 * 64 * 8 * 2);   // 128 KB
  float*    num_p    = (float*)carve((size_t)S * D * 4);
  float*    den_p    = (float*)carve((size_t)S * 4);
  float*    num_c    = (float*)carve((size_t)S * D * 4);
  float*    den_c    = (float*)carve((size_t)S * 4);
  float*    sum_r    = (float*)carve((size_t)S * D * 4);
  float*    outU     = (float*)carve((size_t)S * D * 4);
  int*      degP     = (int*)carve((size_t)S * 4);      // degP/C/R contiguous
  int*      degC     = (int*)carve((size_t)S * 4);
  int*      degR     = (int*)carve((size_t)S * 4);
  int*      bktP     = (int*)carve((size_t)S * CAP * 4);
  int*      bktC     = (int*)carve((size_t)S * CAP * 4);
  int*      bktR     = (int*)carve((size_t)S * CAP * 4);
  int2*     ovf      = (int2*)carve((size_t)3 * OVF_CAP * 8);
  (void)ws_size; (void)n_in; (void)out_size;

  k_setup<<<256, 256, 0, stream>>>(Wp, asp, adp, Wc, asc, adc, bp, bc, bl, Wl, Wr,
                                   vvec, wpack, qid, counters, degP, N, 3 * S);

  k_pre<<<(N * 64 + 255) / 256, 256, 0, stream>>>(s, qid, uniq, counters, S,
                                                  emb, vvec, a_sp, a_dp, a_sc, a_dc,
                                                  ebf, N);

  k_filter<<<dim3((E + 255) / 256, 3), 256, 0, stream>>>(
      eip, eic, eir, qid, bktP, bktC, bktR, degP, degC, degR, ovf, counters, E);

  k_accum<<<dim3((S + 3) / 4, 3), 256, 0, stream>>>(
      bktP, bktC, bktR, degP, degC, degR,
      a_sp, a_dp, a_sc, a_dc, ebf, uniq, counters, ovf,
      num_p, num_c, sum_r, den_p, den_c);

  k_final<<<(S + 15) / 16, 256, 0, stream>>>(num_p, num_c, sum_r, emb, uniq, counters,
                                             a_sp, a_dp, a_sc, a_dc, den_p, den_c, degR,
                                             vvec, wpack, outU);
  k_gather<<<(S * D + 255) / 256, 256, 0, stream>>>(s, qid, outU, out, S);
}

// Round 9
// 199.612 us; speedup vs baseline: 6.0400x; 1.0680x over previous
//
#include <hip/hip_runtime.h>

#define D 128
#define CAP 64
#define OVF_CAP 1024

typedef short bf16x8 __attribute__((ext_vector_type(8)));
typedef float f32x4 __attribute__((ext_vector_type(4)));

__device__ __forceinline__ unsigned short f2bf(float f) {
  unsigned u = __builtin_bit_cast(unsigned, f);
  unsigned r = (u + 0x7fffu + ((u >> 16) & 1u)) >> 16;
  return (unsigned short)r;
}
__device__ __forceinline__ float bflo(unsigned r) {
  return __builtin_bit_cast(float, r << 16);
}
__device__ __forceinline__ float bfhi(unsigned r) {
  return __builtin_bit_cast(float, r & 0xffff0000u);
}
__device__ __forceinline__ float lrelu(float t) {
  return t >= 0.f ? t : 0.2f * t;
}

// ---------------- kernels ----------------

// setup: qid=-1, deg3=0, counters=0, pack Wcat->bf16 fragments, calc_v (block 0)
__global__ void k_setup(const float* __restrict__ Wp, const float* __restrict__ asp,
                        const float* __restrict__ adp, const float* __restrict__ Wc,
                        const float* __restrict__ asc, const float* __restrict__ adc,
                        const float* __restrict__ bp, const float* __restrict__ bc,
                        const float* __restrict__ bl, const float* __restrict__ Wl,
                        const float* __restrict__ Wr,
                        float* __restrict__ v, unsigned short* __restrict__ wpack,
                        int* __restrict__ qid, int* __restrict__ counters,
                        int* __restrict__ deg3, int N, int S3) {
  int i = blockIdx.x * blockDim.x + threadIdx.x;
  int stride = gridDim.x * blockDim.x;
  for (int k = i; k < N; k += stride) qid[k] = -1;
  for (int k = i; k < S3; k += stride) deg3[k] = 0;
  if (i < 16) counters[i] = 0;

  // wpack[((kt*8+nt)*64+lane)*8+j] = Wcat[kt*32+(lane>>4)*8+j][nt*16+(lane&15)]
  for (int idx = i; idx < 16 * 8 * 64 * 8; idx += stride) {
    int j    = idx & 7;
    int lane = (idx >> 3) & 63;
    int nt   = (idx >> 9) & 7;
    int kt   = idx >> 12;
    int o = kt >> 2;
    int c = (kt & 3) * 32 + (lane >> 4) * 8 + j;
    int n = nt * 16 + (lane & 15);
    const float* W = (o == 0) ? Wp : (o == 1) ? Wc : (o == 2) ? Wl : Wr;
    wpack[idx] = f2bf(W[c * D + n]);
  }

  if (blockIdx.x == 0 && threadIdx.x < 128) {
    int k = threadIdx.x;
    float s0 = 0.f, s1 = 0.f, s2 = 0.f, s3 = 0.f;
    for (int d = 0; d < D; ++d) {
      float wp = Wp[k * D + d], wc = Wc[k * D + d];
      s0 += wp * asp[d]; s1 += wp * adp[d];
      s2 += wc * asc[d]; s3 += wc * adc[d];
    }
    v[k] = s0; v[D + k] = s1; v[2 * D + k] = s2; v[3 * D + k] = s3;
    v[4 * D + k] = bp[k] + bc[k] + bl[k];
  }
}

// build_qid (first S threads) + attention scalars + bf16 emb copy.
// One wave handles TWO nodes: 32 lanes x float4 per node row.
__global__ void k_pre(const int* __restrict__ s, int* __restrict__ qid,
                      int* __restrict__ uniq, int* __restrict__ counters, int S,
                      const float* __restrict__ emb, const float* __restrict__ v,
                      float* __restrict__ a_sp, float* __restrict__ a_dp,
                      float* __restrict__ a_sc, float* __restrict__ a_dc,
                      unsigned* __restrict__ ebf, int N) {
  int gtid = blockIdx.x * blockDim.x + threadIdx.x;
  if (gtid < S) {
    int n = s[gtid];
    if (atomicCAS(&qid[n], -1, -2) == -1) {
      int u = atomicAdd(&counters[0], 1);
      uniq[u] = n;
      qid[n] = u;
    }
  }
  int lane = threadIdx.x & 63;
  int node = (gtid >> 6) * 2 + (lane >> 5);
  int c = lane & 31;                       // float4 chunk within row
  if (node >= N) return;
  float4 x4 = ((const float4*)(emb + (size_t)node * D))[c];
  uint2 p;
  p.x = ((unsigned)f2bf(x4.x)) | (((unsigned)f2bf(x4.y)) << 16);
  p.y = ((unsigned)f2bf(x4.z)) | (((unsigned)f2bf(x4.w)) << 16);
  ((uint2*)ebf)[(size_t)node * 32 + c] = p;
  float4 v0 = ((const float4*)(v))[c];
  float4 v1 = ((const float4*)(v + D))[c];
  float4 v2 = ((const float4*)(v + 2 * D))[c];
  float4 v3 = ((const float4*)(v + 3 * D))[c];
  float s0 = x4.x * v0.x + x4.y * v0.y + x4.z * v0.z + x4.w * v0.w;
  float s1 = x4.x * v1.x + x4.y * v1.y + x4.z * v1.z + x4.w * v1.w;
  float s2 = x4.x * v2.x + x4.y * v2.y + x4.z * v2.z + x4.w * v2.w;
  float s3 = x4.x * v3.x + x4.y * v3.y + x4.z * v3.z + x4.w * v3.w;
#pragma unroll
  for (int o = 16; o > 0; o >>= 1) {
    s0 += __shfl_down(s0, o);
    s1 += __shfl_down(s1, o);
    s2 += __shfl_down(s2, o);
    s3 += __shfl_down(s3, o);
  }
  if (c == 0) { a_sp[node] = s0; a_dp[node] = s1; a_sc[node] = s2; a_dc[node] = s3; }
}

// direct-bucket filter (blockIdx.y = relation): bucket[u*CAP+pos]=src, deg[u]++
__global__ void __launch_bounds__(256) k_filter(
    const int* __restrict__ eiP, const int* __restrict__ eiC, const int* __restrict__ eiR,
    const int* __restrict__ qid,
    int* __restrict__ bktP, int* __restrict__ bktC, int* __restrict__ bktR,
    int* __restrict__ degP, int* __restrict__ degC, int* __restrict__ degR,
    int2* __restrict__ ovf, int* __restrict__ counters, int E) {
  int rel = blockIdx.y;
  const int* ei = (rel == 0) ? eiP : (rel == 1) ? eiC : eiR;
  int* bkt      = (rel == 0) ? bktP : (rel == 1) ? bktC : bktR;
  int* deg      = (rel == 0) ? degP : (rel == 1) ? degC : degR;
  int e = blockIdx.x * 256 + threadIdx.x;
  if (e >= E) return;
  int dst = ei[E + e];
  int u = qid[dst];
  if (u < 0) return;
  int src = ei[e];
  int pos = atomicAdd(&deg[u], 1);
  if (pos < CAP) {
    bkt[u * CAP + pos] = src;
  } else {
    int o = atomicAdd(&counters[4 + rel], 1);
    if (o < OVF_CAP) { int2 t; t.x = src; t.y = u; ovf[rel * OVF_CAP + o] = t; }
  }
}

// fused gather+final: per 16-u tile, each wave aggregates 4 u-rows across all
// 3 relations (register acc, bf16 gathers), stages z-rows into LDS A-fragments,
// then MFMA against packed Wcat. outU[u] = ([zP|zC|zR|x]@Wcat)/3 + bias/3.
__global__ void __launch_bounds__(256) k_fused(
    const int* __restrict__ bktP, const int* __restrict__ bktC, const int* __restrict__ bktR,
    const int* __restrict__ degP, const int* __restrict__ degC, const int* __restrict__ degR,
    const float* __restrict__ a_sp, const float* __restrict__ a_dp,
    const float* __restrict__ a_sc, const float* __restrict__ a_dc,
    const unsigned* __restrict__ ebf, const float* __restrict__ emb,
    const int* __restrict__ uniq, const int* __restrict__ counters,
    const int2* __restrict__ ovf, const float* __restrict__ vvec,
    const unsigned short* __restrict__ wpack, float* __restrict__ outU) {
  __shared__ unsigned short A_lds[16 * 64 * 8];   // 16 KB
  int U = counters[0];
  int u0 = blockIdx.x * 16;
  if (u0 >= U) return;
  int tid = threadIdx.x;
  int w = tid >> 6;
  int lane = tid & 63;

  const int* bkts[3] = {bktP, bktC, bktR};
  const int* degs[3] = {degP, degC, degR};
  int Lc[3];
#pragma unroll
  for (int r = 0; r < 3; ++r) {
    int L = counters[4 + r];
    Lc[r] = (L > OVF_CAP) ? OVF_CAP : L;
  }

  for (int t = 0; t < 4; ++t) {
    int m = 4 * w + t;
    int u = u0 + m;
    float2 z[4];
    if (u < U) {
      int n = uniq[u];
      float2 x2 = ((const float2*)(emb + (size_t)n * D))[lane];
      float2 acc[3];
      float den[2];
#pragma unroll
      for (int r = 0; r < 3; ++r) {
        int dg = degs[r][u];
        int mc = (dg < CAP) ? dg : CAP;
        const int* b0 = bkts[r] + u * CAP;
        int srcl = (lane < mc) ? b0[lane] : 0;
        float wl = 0.f;
        float adn = 0.f;
        const float* a_s = (r == 0) ? a_sp : a_sc;
        if (r < 2) {
          adn = ((r == 0) ? a_dp : a_dc)[n];
          if (lane < mc) wl = __expf(lrelu(a_s[srcl] + adn));
        } else {
          wl = (lane < mc) ? 1.f : 0.f;
        }
        float2 a; a.x = 0.f; a.y = 0.f;
        int i = 0;
        for (; i + 4 <= mc; i += 4) {
          int s0 = __shfl(srcl, i),     s1 = __shfl(srcl, i + 1);
          int s2 = __shfl(srcl, i + 2), s3 = __shfl(srcl, i + 3);
          float w0 = __shfl(wl, i),     w1 = __shfl(wl, i + 1);
          float w2 = __shfl(wl, i + 2), w3 = __shfl(wl, i + 3);
          unsigned r0 = ebf[(size_t)s0 * 64 + lane];
          unsigned r1 = ebf[(size_t)s1 * 64 + lane];
          unsigned r2 = ebf[(size_t)s2 * 64 + lane];
          unsigned r3 = ebf[(size_t)s3 * 64 + lane];
          a.x += w0 * bflo(r0) + w1 * bflo(r1) + w2 * bflo(r2) + w3 * bflo(r3);
          a.y += w0 * bfhi(r0) + w1 * bfhi(r1) + w2 * bfhi(r2) + w3 * bfhi(r3);
        }
        for (; i < mc; ++i) {
          int si = __shfl(srcl, i);
          float wi = __shfl(wl, i);
          unsigned rr = ebf[(size_t)si * 64 + lane];
          a.x += wi * bflo(rr);
          a.y += wi * bfhi(rr);
        }
        // overflow fixup (statistically never taken)
        float denx = 0.f;
        if (dg > CAP) {
          for (int l = 0; l < Lc[r]; ++l) {
            int2 ov = ovf[r * OVF_CAP + l];
            if (ov.y == u) {
              float wv = 1.f;
              if (r < 2) wv = __expf(lrelu(a_s[ov.x] + adn));
              unsigned rr = ebf[(size_t)ov.x * 64 + lane];
              a.x += wv * bflo(rr);
              a.y += wv * bfhi(rr);
              denx += wv;
            }
          }
        }
        if (r < 2) {
          float dsum = wl;
#pragma unroll
          for (int o = 32; o > 0; o >>= 1) dsum += __shfl_down(dsum, o);
          den[r] = __shfl(dsum, 0) + denx;
        } else {
          float dgc = (float)dg; if (dgc < 1.f) dgc = 1.f;
          a.x *= (1.f / dgc); a.y *= (1.f / dgc);
        }
        acc[r] = a;
      }
      float wP = __expf(lrelu(a_sp[n] + a_dp[n]));
      float rP = 1.f / (den[0] + wP);
      float wC = __expf(lrelu(a_sc[n] + a_dc[n]));
      float rC = 1.f / (den[1] + wC);
      z[0].x = (acc[0].x + wP * x2.x) * rP; z[0].y = (acc[0].y + wP * x2.y) * rP;
      z[1].x = (acc[1].x + wC * x2.x) * rC; z[1].y = (acc[1].y + wC * x2.y) * rC;
      z[2] = acc[2];
      z[3] = x2;
    } else {
      z[0].x = 0.f; z[0].y = 0.f; z[1] = z[0]; z[2] = z[0]; z[3] = z[0];
    }
    // LDS A-fragment write: columns c=2*lane, 2*lane+1 of operand o
    int ktc = lane >> 4;
    int q = (lane >> 2) & 3;
    int j0 = 2 * (lane & 3);
#pragma unroll
    for (int o = 0; o < 4; ++o) {
      int kt = o * 4 + ktc;
      unsigned pk = ((unsigned)f2bf(z[o].x)) | (((unsigned)f2bf(z[o].y)) << 16);
      *(unsigned*)&A_lds[(kt * 64 + q * 16 + m) * 8 + j0] = pk;
    }
  }
  __syncthreads();

  f32x4 acc0 = {0.f, 0.f, 0.f, 0.f};
  f32x4 acc1 = {0.f, 0.f, 0.f, 0.f};
  const bf16x8* wp = (const bf16x8*)wpack;
#pragma unroll
  for (int kt = 0; kt < 16; ++kt) {
    bf16x8 a  = *(const bf16x8*)&A_lds[(kt * 64 + lane) * 8];
    bf16x8 b0 = wp[(kt * 8 + 2 * w) * 64 + lane];
    bf16x8 b1 = wp[(kt * 8 + 2 * w + 1) * 64 + lane];
    acc0 = __builtin_amdgcn_mfma_f32_16x16x32_bf16(a, b0, acc0, 0, 0, 0);
    acc1 = __builtin_amdgcn_mfma_f32_16x16x32_bf16(a, b1, acc1, 0, 0, 0);
  }

  int col0 = 2 * w * 16 + (lane & 15);
  int col1 = col0 + 16;
  int r0 = (lane >> 4) * 4;
  float b0v = vvec[4 * D + col0] * (1.f / 3.f);
  float b1v = vvec[4 * D + col1] * (1.f / 3.f);
#pragma unroll
  for (int reg = 0; reg < 4; ++reg) {
    int u = u0 + r0 + reg;
    if (u < U) {
      outU[(size_t)u * D + col0] = acc0[reg] * (1.f / 3.f) + b0v;
      outU[(size_t)u * D + col1] = acc1[reg] * (1.f / 3.f) + b1v;
    }
  }
}

// pure gather (bias and /3 already folded into outU)
__global__ void k_gather(const int* __restrict__ s, const int* __restrict__ qid,
                         const float* __restrict__ outU, float* __restrict__ out, int S) {
  int idx = blockIdx.x * blockDim.x + threadIdx.x;
  if (idx >= S * D) return;
  int i = idx >> 7;
  int d = idx & (D - 1);
  int u = qid[s[i]];
  out[idx] = outU[(size_t)u * D + d];
}

// ---------------- launch ----------------

extern "C" void kernel_launch(void* const* d_in, const int* in_sizes, int n_in,
                              void* d_out, int out_size, void* d_ws, size_t ws_size,
                              hipStream_t stream) {
  const int*   s   = (const int*)d_in[0];
  const int*   eip = (const int*)d_in[3];
  const int*   eic = (const int*)d_in[4];
  const int*   eir = (const int*)d_in[5];
  const float* emb = (const float*)d_in[6];
  const float* Wp  = (const float*)d_in[7];
  const float* asp = (const float*)d_in[8];
  const float* adp = (const float*)d_in[9];
  const float* bp  = (const float*)d_in[10];
  const float* Wc  = (const float*)d_in[11];
  const float* asc = (const float*)d_in[12];
  const float* adc = (const float*)d_in[13];
  const float* bc  = (const float*)d_in[14];
  const float* Wl  = (const float*)d_in[15];
  const float* bl  = (const float*)d_in[16];
  const float* Wr  = (const float*)d_in[17];
  float* out = (float*)d_out;

  const int S = in_sizes[0];
  const int E = in_sizes[3] / 2;
  const int N = in_sizes[6] / D;

  char* base = (char*)d_ws;
  size_t off = 0;
  auto carve = [&](size_t bytes) -> char* {
    char* q = base + off;
    off += (bytes + 255) & ~(size_t)255;
    return q;
  };
  float*    a_sp     = (float*)carve((size_t)N * 4);
  float*    a_dp     = (float*)carve((size_t)N * 4);
  float*    a_sc     = (float*)carve((size_t)N * 4);
  float*    a_dc     = (float*)carve((size_t)N * 4);
  int*      qid      = (int*)carve((size_t)N * 4);
  unsigned* ebf      = (unsigned*)carve((size_t)N * 64 * 4);   // 25.6 MB bf16 emb
  int*      uniq     = (int*)carve((size_t)S * 4);
  int*      counters = (int*)carve(64);    // [0]=U [4..6]=overflow counts
  float*    vvec     = (float*)carve(5 * D * 4);
  unsigned short* wpack = (unsigned short*)carve((size_t)16 * 8 * 64 * 8 * 2);  // 128 KB
  float*    outU     = (float*)carve((size_t)S * D * 4);
  int*      degP     = (int*)carve((size_t)S * 4);      // degP/C/R contiguous
  int*      degC     = (int*)carve((size_t)S * 4);
  int*      degR     = (int*)carve((size_t)S * 4);
  int*      bktP     = (int*)carve((size_t)S * CAP * 4);
  int*      bktC     = (int*)carve((size_t)S * CAP * 4);
  int*      bktR     = (int*)carve((size_t)S * CAP * 4);
  int2*     ovf      = (int2*)carve((size_t)3 * OVF_CAP * 8);
  (void)ws_size; (void)n_in; (void)out_size;

  k_setup<<<256, 256, 0, stream>>>(Wp, asp, adp, Wc, asc, adc, bp, bc, bl, Wl, Wr,
                                   vvec, wpack, qid, counters, degP, N, 3 * S);

  k_pre<<<(N * 32 + 255) / 256, 256, 0, stream>>>(s, qid, uniq, counters, S,
                                                  emb, vvec, a_sp, a_dp, a_sc, a_dc,
                                                  ebf, N);

  k_filter<<<dim3((E + 255) / 256, 3), 256, 0, stream>>>(
      eip, eic, eir, qid, bktP, bktC, bktR, degP, degC, degR, ovf, counters, E);

  k_fused<<<(S + 15) / 16, 256, 0, stream>>>(
      bktP, bktC, bktR, degP, degC, degR,
      a_sp, a_dp, a_sc, a_dc, ebf, emb, uniq, counters, ovf,
      vvec, wpack, outU);

  k_gather<<<(S * D + 255) / 256, 256, 0, stream>>>(s, qid, outU, out, S);
}